// Round 1
// baseline (798.059 us; speedup 1.0000x reference)
//
#include <hip/hip_runtime.h>

// Fused GQA prefill: QKV proj -> RoPE(Q,K) -> causal flash attention -> O proj.
// B=1, T=2048, HID=4096, H=32, HKV=8, DH=128, pos=0 (validated input), so the
// KV cache never contributes (window == fresh K/V).
// All GEMMs: bf16 MFMA 16x16x32, fp32 accum; fp32->bf16 conversion fused into
// register-staged LDS writes. XOR swizzle (byte ^= (row&7)<<4) on both LDS
// write and read sides.

#define DEVI __device__ __forceinline__

typedef __attribute__((ext_vector_type(8))) short short8;
typedef __attribute__((ext_vector_type(4))) float f32x4;

DEVI unsigned short f2bf(float f) {
  union { float f; unsigned u; } x; x.f = f;
  unsigned r = x.u + 0x7FFFu + ((x.u >> 16) & 1u);
  return (unsigned short)(r >> 16);
}
DEVI float bf2f(unsigned short h) {
  union { unsigned u; float f; } x; x.u = ((unsigned)h) << 16;
  return x.f;
}
DEVI f32x4 mfma16(short8 a, short8 b, f32x4 c) {
  return __builtin_amdgcn_mfma_f32_16x16x32_bf16(a, b, c, 0, 0, 0);
}

// ---------------------------------------------------------------------------
// GEMM 1: QKV projection. C[m][n] = sum_k hs[m][k] * W[n][k], split across
// Wq/Wk/Wv by n-tile. Output bf16 (pre-RoPE for Q,K).
// Tile 128x128, BK=64, 4 waves, each wave a 64x64 quadrant (4x4 frags).
// ---------------------------------------------------------------------------
__global__ __launch_bounds__(256, 2)
void gemm_qkv_kernel(const float* __restrict__ hs,
                     const float* __restrict__ Wq,
                     const float* __restrict__ Wk,
                     const float* __restrict__ Wv,
                     unsigned short* __restrict__ Qb,
                     unsigned short* __restrict__ Kb,
                     unsigned short* __restrict__ Vb) {
  const int K = 4096;
  __shared__ __align__(16) unsigned short As[128][64];
  __shared__ __align__(16) unsigned short Bs[128][64];
  const int tid = threadIdx.x;
  const int lane = tid & 63, wid = tid >> 6;
  const int m0 = blockIdx.y * 128;
  const int n0g = blockIdx.x * 128;

  const float* Bsrc; unsigned short* outp; int ldo, oc;
  if (n0g < 4096)      { Bsrc = Wq + (size_t)n0g * K;          outp = Qb; ldo = 4096; oc = n0g; }
  else if (n0g < 5120) { Bsrc = Wk + (size_t)(n0g - 4096) * K; outp = Kb; ldo = 1024; oc = n0g - 4096; }
  else                 { Bsrc = Wv + (size_t)(n0g - 5120) * K; outp = Vb; ldo = 1024; oc = n0g - 5120; }
  const float* Asrc = hs + (size_t)m0 * K;

  f32x4 acc[4][4];
#pragma unroll
  for (int i = 0; i < 4; ++i)
#pragma unroll
    for (int j = 0; j < 4; ++j) acc[i][j] = (f32x4){0.f, 0.f, 0.f, 0.f};

  const int wm = (wid >> 1) * 64, wn = (wid & 1) * 64;

  for (int k0 = 0; k0 < K; k0 += 64) {
    // stage: 128x64 fp32 -> bf16 LDS, both A and B. 2048 float4 chunks each.
#pragma unroll
    for (int c = 0; c < 8; ++c) {
      int i4 = tid + c * 256;            // 0..2047
      int row = i4 >> 4;                 // 16 float4 per 64-col row
      int col4 = (i4 & 15) << 2;
      float4 va = *(const float4*)(Asrc + (size_t)row * K + k0 + col4);
      float4 vb = *(const float4*)(Bsrc + (size_t)row * K + k0 + col4);
      ushort4 ha; ha.x = f2bf(va.x); ha.y = f2bf(va.y); ha.z = f2bf(va.z); ha.w = f2bf(va.w);
      ushort4 hb; hb.x = f2bf(vb.x); hb.y = f2bf(vb.y); hb.z = f2bf(vb.z); hb.w = f2bf(vb.w);
      int bo = (col4 * 2) ^ ((row & 7) << 4);
      *(ushort4*)((char*)(&As[row][0]) + bo) = ha;
      *(ushort4*)((char*)(&Bs[row][0]) + bo) = hb;
    }
    __syncthreads();
#pragma unroll
    for (int ks = 0; ks < 2; ++ks) {
      short8 af[4], bfr[4];
      const int co = ks * 64 + ((lane >> 4) << 4);
#pragma unroll
      for (int i = 0; i < 4; ++i) {
        int ar = wm + i * 16 + (lane & 15);
        af[i] = *(const short8*)((const char*)(&As[ar][0]) + (co ^ ((ar & 7) << 4)));
        int br = wn + i * 16 + (lane & 15);
        bfr[i] = *(const short8*)((const char*)(&Bs[br][0]) + (co ^ ((br & 7) << 4)));
      }
#pragma unroll
      for (int i = 0; i < 4; ++i)
#pragma unroll
        for (int j = 0; j < 4; ++j)
          acc[i][j] = mfma16(af[i], bfr[j], acc[i][j]);
    }
    __syncthreads();
  }

#pragma unroll
  for (int i = 0; i < 4; ++i) {
    int rb = m0 + wm + i * 16 + ((lane >> 4) << 2);
#pragma unroll
    for (int j = 0; j < 4; ++j) {
      int cb = oc + wn + j * 16 + (lane & 15);
#pragma unroll
      for (int r = 0; r < 4; ++r)
        outp[(size_t)(rb + r) * ldo + cb] = f2bf(acc[i][j][r]);
    }
  }
}

// ---------------------------------------------------------------------------
// RoPE in place on bf16 Q and K. One thread per rotation pair (d, d+64).
// ---------------------------------------------------------------------------
__global__ __launch_bounds__(256)
void rope_kernel(unsigned short* __restrict__ Qb, unsigned short* __restrict__ Kb,
                 const int* __restrict__ posp) {
  const int QP = 2048 * 32 * 64;
  const int KP = 2048 * 8 * 64;
  int idx = blockIdx.x * 256 + threadIdx.x;
  if (idx >= QP + KP) return;
  unsigned short* base; int t, hh, d, ld;
  if (idx < QP) {
    base = Qb; ld = 4096;
    t = idx >> 11; int rem = idx & 2047; hh = rem >> 6; d = rem & 63;
  } else {
    int j = idx - QP; base = Kb; ld = 1024;
    t = j >> 9; int rem = j & 511; hh = rem >> 6; d = rem & 63;
  }
  // freq = 500000^(-2d/128) = 2^(-d * log2(500000)/64)
  float freq = exp2f(-(float)d * 0.29580575880077f);
  float ang = (float)(t + posp[0]) * freq;
  float s, c;
  __sincosf(ang, &s, &c);
  size_t i1 = (size_t)t * ld + hh * 128 + d;
  float x1 = bf2f(base[i1]), x2 = bf2f(base[i1 + 64]);
  base[i1]      = f2bf(x1 * c - x2 * s);
  base[i1 + 64] = f2bf(x1 * s + x2 * c);
}

// ---------------------------------------------------------------------------
// Causal GQA flash attention. Block = (q-tile of 128, head). 4 waves, each
// owns 32 q-rows. KV tile = 64. Q held in registers for the whole kernel.
// ---------------------------------------------------------------------------
__global__ __launch_bounds__(256)
void attn_kernel(const unsigned short* __restrict__ Qb,
                 const unsigned short* __restrict__ Kb,
                 const unsigned short* __restrict__ Vb,
                 unsigned short* __restrict__ Ob) {
  __shared__ __align__(16) unsigned short Ks[64][128];   // [s][d]
  __shared__ __align__(16) unsigned short Vt[128][64];   // [d][s] (transposed)
  __shared__ __align__(16) unsigned short Ps[4][32][64]; // per-wave P
  const int tid = threadIdx.x, lane = tid & 63, wid = tid >> 6;
  const int qt = blockIdx.x, h = blockIdx.y;
  const int kh = h >> 2;
  const int q0 = qt * 128;
  const float SCALE = 0.08838834764831845f;

  // Q fragments: rows = q0 + wid*32 + mi*16 + (lane&15), k-dim = head dims
  short8 aq[2][4];
  const int qrow_f = q0 + wid * 32 + (lane & 15);
#pragma unroll
  for (int mi = 0; mi < 2; ++mi)
#pragma unroll
    for (int ks = 0; ks < 4; ++ks)
      aq[mi][ks] = *(const short8*)(Qb + (size_t)(qrow_f + mi * 16) * 4096
                                    + h * 128 + ks * 32 + ((lane >> 4) << 3));

  f32x4 o_acc[2][8];
#pragma unroll
  for (int mi = 0; mi < 2; ++mi)
#pragma unroll
    for (int n8 = 0; n8 < 8; ++n8) o_acc[mi][n8] = (f32x4){0.f, 0.f, 0.f, 0.f};
  float mstate[2][4], lstate[2][4];
#pragma unroll
  for (int mi = 0; mi < 2; ++mi)
#pragma unroll
    for (int r = 0; r < 4; ++r) { mstate[mi][r] = -1e30f; lstate[mi][r] = 0.f; }

  const int ntiles = 2 * (qt + 1);
  for (int st = 0; st < ntiles; ++st) {
    const int s0 = st * 64;
    // stage K [64][128] and V transposed [128][64], swizzled
#pragma unroll
    for (int c = 0; c < 8; ++c) {
      int i4 = tid + c * 256;            // 0..2047 ushort4 chunks
      int s = i4 >> 5;                   // 32 chunks per 128-col row
      int d4 = (i4 & 31) << 2;
      ushort4 kv = *(const ushort4*)(Kb + (size_t)(s0 + s) * 1024 + kh * 128 + d4);
      *(ushort4*)((char*)(&Ks[s][0]) + ((d4 * 2) ^ ((s & 7) << 4))) = kv;
      ushort4 vv = *(const ushort4*)(Vb + (size_t)(s0 + s) * 1024 + kh * 128 + d4);
      const unsigned short* vp = (const unsigned short*)&vv;
#pragma unroll
      for (int j = 0; j < 4; ++j) {
        int dd = d4 + j;
        *(unsigned short*)((char*)(&Vt[dd][0]) + ((s * 2) ^ ((dd & 7) << 4))) = vp[j];
      }
    }
    __syncthreads();

    // S = Q K^T (32 q-rows x 64 keys per wave)
    f32x4 sacc[2][4];
#pragma unroll
    for (int mi = 0; mi < 2; ++mi)
#pragma unroll
      for (int ni = 0; ni < 4; ++ni) sacc[mi][ni] = (f32x4){0.f, 0.f, 0.f, 0.f};
#pragma unroll
    for (int ks = 0; ks < 4; ++ks) {
      short8 bk[4];
      const int co = ks * 64 + ((lane >> 4) << 4);
#pragma unroll
      for (int ni = 0; ni < 4; ++ni) {
        int kr = ni * 16 + (lane & 15);
        bk[ni] = *(const short8*)((const char*)(&Ks[kr][0]) + (co ^ ((kr & 7) << 4)));
      }
#pragma unroll
      for (int mi = 0; mi < 2; ++mi)
#pragma unroll
        for (int ni = 0; ni < 4; ++ni)
          sacc[mi][ni] = mfma16(aq[mi][ks], bk[ni], sacc[mi][ni]);
    }

    // online softmax; write P (bf16) to this wave's LDS region
    unsigned short* pbase = &Ps[wid][0][0];
#pragma unroll
    for (int mi = 0; mi < 2; ++mi) {
#pragma unroll
      for (int r = 0; r < 4; ++r) {
        int qrow = q0 + wid * 32 + mi * 16 + ((lane >> 4) << 2) + r;
        float vv4[4]; float vmax = -1e30f;
#pragma unroll
        for (int ni = 0; ni < 4; ++ni) {
          int scol = s0 + ni * 16 + (lane & 15);
          float x = sacc[mi][ni][r] * SCALE;
          if (scol > qrow) x = -1e30f;
          vv4[ni] = x; vmax = fmaxf(vmax, x);
        }
        vmax = fmaxf(vmax, __shfl_xor(vmax, 1));
        vmax = fmaxf(vmax, __shfl_xor(vmax, 2));
        vmax = fmaxf(vmax, __shfl_xor(vmax, 4));
        vmax = fmaxf(vmax, __shfl_xor(vmax, 8));
        float mo = mstate[mi][r];
        float mn = fmaxf(mo, vmax);
        float al = __expf(mo - mn);
        float rs = 0.f;
        int prow = mi * 16 + ((lane >> 4) << 2) + r;
#pragma unroll
        for (int ni = 0; ni < 4; ++ni) {
          float p = __expf(vv4[ni] - mn);
          rs += p;
          int pb = (prow * 128 + (ni * 16 + (lane & 15)) * 2) ^ ((prow & 7) << 4);
          *(unsigned short*)((char*)pbase + pb) = f2bf(p);
        }
        rs += __shfl_xor(rs, 1);
        rs += __shfl_xor(rs, 2);
        rs += __shfl_xor(rs, 4);
        rs += __shfl_xor(rs, 8);
        lstate[mi][r] = lstate[mi][r] * al + rs;
        mstate[mi][r] = mn;
#pragma unroll
        for (int n8 = 0; n8 < 8; ++n8) o_acc[mi][n8][r] *= al;
      }
    }

    // O += P V   (P: 32x64 from own-wave LDS; V via transposed tile)
#pragma unroll
    for (int ks2 = 0; ks2 < 2; ++ks2) {
      const int co = ks2 * 64 + ((lane >> 4) << 4);
      short8 pa[2];
#pragma unroll
      for (int mi = 0; mi < 2; ++mi) {
        int pr = mi * 16 + (lane & 15);
        pa[mi] = *(const short8*)((const char*)(&Ps[wid][pr][0]) + (co ^ ((pr & 7) << 4)));
      }
#pragma unroll
      for (int n8 = 0; n8 < 8; ++n8) {
        int vr = n8 * 16 + (lane & 15);
        short8 bv = *(const short8*)((const char*)(&Vt[vr][0]) + (co ^ ((vr & 7) << 4)));
#pragma unroll
        for (int mi = 0; mi < 2; ++mi)
          o_acc[mi][n8] = mfma16(pa[mi], bv, o_acc[mi][n8]);
      }
    }
    __syncthreads();
  }

  // epilogue: normalize and store bf16
#pragma unroll
  for (int mi = 0; mi < 2; ++mi) {
#pragma unroll
    for (int r = 0; r < 4; ++r) {
      float inv = 1.0f / lstate[mi][r];
      int row = q0 + wid * 32 + mi * 16 + ((lane >> 4) << 2) + r;
#pragma unroll
      for (int n8 = 0; n8 < 8; ++n8)
        Ob[(size_t)row * 4096 + h * 128 + n8 * 16 + (lane & 15)] =
            f2bf(o_acc[mi][n8][r] * inv);
    }
  }
}

// ---------------------------------------------------------------------------
// GEMM 2: output projection. C[m][n] = sum_k AO[m][k] * Wo[n][k]. A is bf16,
// B fp32 (converted in staging), C fp32 to d_out.
// ---------------------------------------------------------------------------
__global__ __launch_bounds__(256, 2)
void gemm_out_kernel(const unsigned short* __restrict__ Ab,
                     const float* __restrict__ Wo,
                     float* __restrict__ Cout) {
  const int K = 4096;
  __shared__ __align__(16) unsigned short As[128][64];
  __shared__ __align__(16) unsigned short Bs[128][64];
  const int tid = threadIdx.x;
  const int lane = tid & 63, wid = tid >> 6;
  const int m0 = blockIdx.y * 128;
  const int n0 = blockIdx.x * 128;

  f32x4 acc[4][4];
#pragma unroll
  for (int i = 0; i < 4; ++i)
#pragma unroll
    for (int j = 0; j < 4; ++j) acc[i][j] = (f32x4){0.f, 0.f, 0.f, 0.f};

  const int wm = (wid >> 1) * 64, wn = (wid & 1) * 64;

  for (int k0 = 0; k0 < K; k0 += 64) {
#pragma unroll
    for (int c = 0; c < 8; ++c) {
      int i4 = tid + c * 256;
      int row = i4 >> 4;
      int col4 = (i4 & 15) << 2;
      ushort4 ha = *(const ushort4*)(Ab + (size_t)(m0 + row) * K + k0 + col4);
      float4 vb = *(const float4*)(Wo + (size_t)(n0 + row) * K + k0 + col4);
      ushort4 hb; hb.x = f2bf(vb.x); hb.y = f2bf(vb.y); hb.z = f2bf(vb.z); hb.w = f2bf(vb.w);
      int bo = (col4 * 2) ^ ((row & 7) << 4);
      *(ushort4*)((char*)(&As[row][0]) + bo) = ha;
      *(ushort4*)((char*)(&Bs[row][0]) + bo) = hb;
    }
    __syncthreads();
#pragma unroll
    for (int ks = 0; ks < 2; ++ks) {
      short8 af[4], bfr[4];
      const int co = ks * 64 + ((lane >> 4) << 4);
#pragma unroll
      for (int i = 0; i < 4; ++i) {
        int ar = wm + i * 16 + (lane & 15);
        af[i] = *(const short8*)((const char*)(&As[ar][0]) + (co ^ ((ar & 7) << 4)));
        int br = wn + i * 16 + (lane & 15);
        bfr[i] = *(const short8*)((const char*)(&Bs[br][0]) + (co ^ ((br & 7) << 4)));
      }
#pragma unroll
      for (int i = 0; i < 4; ++i)
#pragma unroll
        for (int j = 0; j < 4; ++j)
          acc[i][j] = mfma16(af[i], bfr[j], acc[i][j]);
    }
    __syncthreads();
  }

#pragma unroll
  for (int i = 0; i < 4; ++i) {
    int rb = m0 + wm + i * 16 + ((lane >> 4) << 2);
#pragma unroll
    for (int j = 0; j < 4; ++j) {
      int cb = n0 + wn + j * 16 + (lane & 15);
#pragma unroll
      for (int r = 0; r < 4; ++r)
        Cout[(size_t)(rb + r) * 4096 + cb] = acc[i][j][r];
    }
  }
}

extern "C" void kernel_launch(void* const* d_in, const int* in_sizes, int n_in,
                              void* d_out, int out_size, void* d_ws, size_t ws_size,
                              hipStream_t stream) {
  const float* hs = (const float*)d_in[0];
  const float* Wq = (const float*)d_in[1];
  const float* Wk = (const float*)d_in[2];
  const float* Wv = (const float*)d_in[3];
  const float* Wo = (const float*)d_in[4];
  const int* pos = (const int*)d_in[7];

  unsigned short* Qb = (unsigned short*)d_ws;          // 2048*4096 bf16
  unsigned short* Kb = Qb + (size_t)2048 * 4096;       // 2048*1024 bf16
  unsigned short* Vb = Kb + (size_t)2048 * 1024;       // 2048*1024 bf16
  unsigned short* Ob = Vb + (size_t)2048 * 1024;       // 2048*4096 bf16
  float* out = (float*)d_out;

  gemm_qkv_kernel<<<dim3(48, 16), 256, 0, stream>>>(hs, Wq, Wk, Wv, Qb, Kb, Vb);
  const int npairs = 2048 * 32 * 64 + 2048 * 8 * 64;
  rope_kernel<<<dim3((npairs + 255) / 256), 256, 0, stream>>>(Qb, Kb, pos);
  attn_kernel<<<dim3(16, 32), 256, 0, stream>>>(Qb, Kb, Vb, Ob);
  gemm_out_kernel<<<dim3(32, 16), 256, 0, stream>>>(Ob, Wo, out);
}

// Round 5
// 578.875 us; speedup vs baseline: 1.3786x; 1.3786x over previous
//
#include <hip/hip_runtime.h>

// Fused GQA prefill: cvt(fp32->bf16) -> QKV proj -> RoPE -> causal flash attn
// -> O proj.  B=1, T=2048, HID=4096, H=32, HKV=8, DH=128, pos=0.
// GEMMs use the m97 structure: global_load_lds(16B) staging into linear LDS,
// 128x128 tile, BK=64, 4 waves x 64x64 quadrant, bf16 MFMA 16x16x32.

#define DEVI __device__ __forceinline__

typedef __attribute__((ext_vector_type(8))) short short8;
typedef __attribute__((ext_vector_type(4))) float f32x4;

DEVI unsigned short f2bf(float f) {
  union { float f; unsigned u; } x; x.f = f;
  unsigned r = x.u + 0x7FFFu + ((x.u >> 16) & 1u);
  return (unsigned short)(r >> 16);
}
DEVI float bf2f(unsigned short h) {
  union { unsigned u; float f; } x; x.u = ((unsigned)h) << 16;
  return x.f;
}
DEVI f32x4 mfma16(short8 a, short8 b, f32x4 c) {
  return __builtin_amdgcn_mfma_f32_16x16x32_bf16(a, b, c, 0, 0, 0);
}
DEVI void gl2lds16(const unsigned short* g, unsigned short* l) {
  __builtin_amdgcn_global_load_lds(
      (const __attribute__((address_space(1))) unsigned int*)g,
      (__attribute__((address_space(3))) unsigned int*)l, 16, 0, 0);
}

// ---------------------------------------------------------------------------
// fp32 -> bf16 conversion (memory-bound, vectorized float4 -> ushort4)
// ---------------------------------------------------------------------------
__global__ __launch_bounds__(256)
void cvt_kernel(const float* __restrict__ src, unsigned short* __restrict__ dst,
                int n4) {
  int i = blockIdx.x * 256 + threadIdx.x;
  const int stride = gridDim.x * 256;
  for (; i < n4; i += stride) {
    float4 v = ((const float4*)src)[i];
    ushort4 h;
    h.x = f2bf(v.x); h.y = f2bf(v.y); h.z = f2bf(v.z); h.w = f2bf(v.w);
    ((ushort4*)dst)[i] = h;
  }
}

// ---------------------------------------------------------------------------
// GEMM 1 (m97 structure): C[m][n] = sum_k hs[m][k] * W[n][k]; n-tile selects
// Wq/Wk/Wv.  Output bf16 (pre-RoPE for Q,K).
// ---------------------------------------------------------------------------
__global__ __launch_bounds__(256, 2)
void gemm_qkv_bf16(const unsigned short* __restrict__ hsb,
                   const unsigned short* __restrict__ Wqb,
                   const unsigned short* __restrict__ Wkb,
                   const unsigned short* __restrict__ Wvb,
                   unsigned short* __restrict__ Qb,
                   unsigned short* __restrict__ Kb,
                   unsigned short* __restrict__ Vb) {
  const int K = 4096;
  __shared__ __align__(16) unsigned short As[128][64];
  __shared__ __align__(16) unsigned short Bs[128][64];
  const int tid = threadIdx.x, lane = tid & 63, wid = tid >> 6;
  const int m0 = blockIdx.y * 128;
  const int n0g = blockIdx.x * 128;

  const unsigned short* Bsrc; unsigned short* outp; int ldo, oc;
  if (n0g < 4096)      { Bsrc = Wqb + (size_t)n0g * K;          outp = Qb; ldo = 4096; oc = n0g; }
  else if (n0g < 5120) { Bsrc = Wkb + (size_t)(n0g - 4096) * K; outp = Kb; ldo = 1024; oc = n0g - 4096; }
  else                 { Bsrc = Wvb + (size_t)(n0g - 5120) * K; outp = Vb; ldo = 1024; oc = n0g - 5120; }
  const unsigned short* Asrc = hsb + (size_t)m0 * K;

  f32x4 acc[4][4];
#pragma unroll
  for (int i = 0; i < 4; ++i)
#pragma unroll
    for (int j = 0; j < 4; ++j) acc[i][j] = (f32x4){0.f, 0.f, 0.f, 0.f};

  const int wm = (wid >> 1) * 64, wn = (wid & 1) * 64;
  // staging: each wave covers 32 rows (4 x global_load_lds of 1KB = 8 rows)
  const int srow = wid * 32 + (lane >> 3);
  const int scol = (lane & 7) * 8;

  for (int k0 = 0; k0 < K; k0 += 64) {
#pragma unroll
    for (int i = 0; i < 4; ++i) {
      gl2lds16(Asrc + (size_t)(srow + i * 8) * K + k0 + scol, &As[wid * 32 + i * 8][0]);
      gl2lds16(Bsrc + (size_t)(srow + i * 8) * K + k0 + scol, &Bs[wid * 32 + i * 8][0]);
    }
    __syncthreads();
#pragma unroll
    for (int ks = 0; ks < 2; ++ks) {
      short8 af[4], bfr[4];
      const int co = ks * 64 + ((lane >> 4) << 4);
#pragma unroll
      for (int i = 0; i < 4; ++i) {
        af[i]  = *(const short8*)((const char*)(&As[wm + i * 16 + (lane & 15)][0]) + co);
        bfr[i] = *(const short8*)((const char*)(&Bs[wn + i * 16 + (lane & 15)][0]) + co);
      }
#pragma unroll
      for (int i = 0; i < 4; ++i)
#pragma unroll
        for (int j = 0; j < 4; ++j)
          acc[i][j] = mfma16(af[i], bfr[j], acc[i][j]);
    }
    __syncthreads();
  }

#pragma unroll
  for (int i = 0; i < 4; ++i) {
    int rb = m0 + wm + i * 16 + ((lane >> 4) << 2);
#pragma unroll
    for (int j = 0; j < 4; ++j) {
      int cb = oc + wn + j * 16 + (lane & 15);
#pragma unroll
      for (int r = 0; r < 4; ++r)
        outp[(size_t)(rb + r) * ldo + cb] = f2bf(acc[i][j][r]);
    }
  }
}

// ---------------------------------------------------------------------------
// RoPE in place on bf16 Q and K. One thread per rotation pair (d, d+64).
// ---------------------------------------------------------------------------
__global__ __launch_bounds__(256)
void rope_kernel(unsigned short* __restrict__ Qb, unsigned short* __restrict__ Kb,
                 const int* __restrict__ posp) {
  const int QP = 2048 * 32 * 64;
  const int KP = 2048 * 8 * 64;
  int idx = blockIdx.x * 256 + threadIdx.x;
  if (idx >= QP + KP) return;
  unsigned short* base; int t, hh, d, ld;
  if (idx < QP) {
    base = Qb; ld = 4096;
    t = idx >> 11; int rem = idx & 2047; hh = rem >> 6; d = rem & 63;
  } else {
    int j = idx - QP; base = Kb; ld = 1024;
    t = j >> 9; int rem = j & 511; hh = rem >> 6; d = rem & 63;
  }
  float freq = exp2f(-(float)d * 0.29580575880077f);  // 500000^(-2d/128)
  float ang = (float)(t + posp[0]) * freq;
  float s, c;
  __sincosf(ang, &s, &c);
  size_t i1 = (size_t)t * ld + hh * 128 + d;
  float x1 = bf2f(base[i1]), x2 = bf2f(base[i1 + 64]);
  base[i1]      = f2bf(x1 * c - x2 * s);
  base[i1 + 64] = f2bf(x1 * s + x2 * c);
}

// ---------------------------------------------------------------------------
// Causal GQA flash attention. Block = (q-tile of 128, head). 4 waves, each
// owns 32 q-rows. KV tile = 64. Q held in registers for the whole kernel.
// ---------------------------------------------------------------------------
__global__ __launch_bounds__(256)
void attn_kernel(const unsigned short* __restrict__ Qb,
                 const unsigned short* __restrict__ Kb,
                 const unsigned short* __restrict__ Vb,
                 unsigned short* __restrict__ Ob) {
  __shared__ __align__(16) unsigned short Ks[64][128];   // [s][d]
  __shared__ __align__(16) unsigned short Vt[128][64];   // [d][s] (transposed)
  __shared__ __align__(16) unsigned short Ps[4][32][64]; // per-wave P
  const int tid = threadIdx.x, lane = tid & 63, wid = tid >> 6;
  const int qt = blockIdx.x, h = blockIdx.y;
  const int kh = h >> 2;
  const int q0 = qt * 128;
  const float SCALE = 0.08838834764831845f;

  short8 aq[2][4];
  const int qrow_f = q0 + wid * 32 + (lane & 15);
#pragma unroll
  for (int mi = 0; mi < 2; ++mi)
#pragma unroll
    for (int ks = 0; ks < 4; ++ks)
      aq[mi][ks] = *(const short8*)(Qb + (size_t)(qrow_f + mi * 16) * 4096
                                    + h * 128 + ks * 32 + ((lane >> 4) << 3));

  f32x4 o_acc[2][8];
#pragma unroll
  for (int mi = 0; mi < 2; ++mi)
#pragma unroll
    for (int n8 = 0; n8 < 8; ++n8) o_acc[mi][n8] = (f32x4){0.f, 0.f, 0.f, 0.f};
  float mstate[2][4], lstate[2][4];
#pragma unroll
  for (int mi = 0; mi < 2; ++mi)
#pragma unroll
    for (int r = 0; r < 4; ++r) { mstate[mi][r] = -1e30f; lstate[mi][r] = 0.f; }

  const int ntiles = 2 * (qt + 1);
  for (int st = 0; st < ntiles; ++st) {
    const int s0 = st * 64;
#pragma unroll
    for (int c = 0; c < 8; ++c) {
      int i4 = tid + c * 256;
      int s = i4 >> 5;
      int d4 = (i4 & 31) << 2;
      ushort4 kv = *(const ushort4*)(Kb + (size_t)(s0 + s) * 1024 + kh * 128 + d4);
      *(ushort4*)((char*)(&Ks[s][0]) + ((d4 * 2) ^ ((s & 7) << 4))) = kv;
      ushort4 vv = *(const ushort4*)(Vb + (size_t)(s0 + s) * 1024 + kh * 128 + d4);
      const unsigned short* vp = (const unsigned short*)&vv;
#pragma unroll
      for (int j = 0; j < 4; ++j) {
        int dd = d4 + j;
        *(unsigned short*)((char*)(&Vt[dd][0]) + ((s * 2) ^ ((dd & 7) << 4))) = vp[j];
      }
    }
    __syncthreads();

    f32x4 sacc[2][4];
#pragma unroll
    for (int mi = 0; mi < 2; ++mi)
#pragma unroll
      for (int ni = 0; ni < 4; ++ni) sacc[mi][ni] = (f32x4){0.f, 0.f, 0.f, 0.f};
#pragma unroll
    for (int ks = 0; ks < 4; ++ks) {
      short8 bk[4];
      const int co = ks * 64 + ((lane >> 4) << 4);
#pragma unroll
      for (int ni = 0; ni < 4; ++ni) {
        int kr = ni * 16 + (lane & 15);
        bk[ni] = *(const short8*)((const char*)(&Ks[kr][0]) + (co ^ ((kr & 7) << 4)));
      }
#pragma unroll
      for (int mi = 0; mi < 2; ++mi)
#pragma unroll
        for (int ni = 0; ni < 4; ++ni)
          sacc[mi][ni] = mfma16(aq[mi][ks], bk[ni], sacc[mi][ni]);
    }

    unsigned short* pbase = &Ps[wid][0][0];
#pragma unroll
    for (int mi = 0; mi < 2; ++mi) {
#pragma unroll
      for (int r = 0; r < 4; ++r) {
        int qrow = q0 + wid * 32 + mi * 16 + ((lane >> 4) << 2) + r;
        float vv4[4]; float vmax = -1e30f;
#pragma unroll
        for (int ni = 0; ni < 4; ++ni) {
          int scol = s0 + ni * 16 + (lane & 15);
          float x = sacc[mi][ni][r] * SCALE;
          if (scol > qrow) x = -1e30f;
          vv4[ni] = x; vmax = fmaxf(vmax, x);
        }
        vmax = fmaxf(vmax, __shfl_xor(vmax, 1));
        vmax = fmaxf(vmax, __shfl_xor(vmax, 2));
        vmax = fmaxf(vmax, __shfl_xor(vmax, 4));
        vmax = fmaxf(vmax, __shfl_xor(vmax, 8));
        float mo = mstate[mi][r];
        float mn = fmaxf(mo, vmax);
        float al = __expf(mo - mn);
        float rs = 0.f;
        int prow = mi * 16 + ((lane >> 4) << 2) + r;
#pragma unroll
        for (int ni = 0; ni < 4; ++ni) {
          float p = __expf(vv4[ni] - mn);
          rs += p;
          int pb = (prow * 128 + (ni * 16 + (lane & 15)) * 2) ^ ((prow & 7) << 4);
          *(unsigned short*)((char*)pbase + pb) = f2bf(p);
        }
        rs += __shfl_xor(rs, 1);
        rs += __shfl_xor(rs, 2);
        rs += __shfl_xor(rs, 4);
        rs += __shfl_xor(rs, 8);
        lstate[mi][r] = lstate[mi][r] * al + rs;
        mstate[mi][r] = mn;
#pragma unroll
        for (int n8 = 0; n8 < 8; ++n8) o_acc[mi][n8][r] *= al;
      }
    }

#pragma unroll
    for (int ks2 = 0; ks2 < 2; ++ks2) {
      const int co = ks2 * 64 + ((lane >> 4) << 4);
      short8 pa[2];
#pragma unroll
      for (int mi = 0; mi < 2; ++mi) {
        int pr = mi * 16 + (lane & 15);
        pa[mi] = *(const short8*)((const char*)(&Ps[wid][pr][0]) + (co ^ ((pr & 7) << 4)));
      }
#pragma unroll
      for (int n8 = 0; n8 < 8; ++n8) {
        int vr = n8 * 16 + (lane & 15);
        short8 bv = *(const short8*)((const char*)(&Vt[vr][0]) + (co ^ ((vr & 7) << 4)));
#pragma unroll
        for (int mi = 0; mi < 2; ++mi)
          o_acc[mi][n8] = mfma16(pa[mi], bv, o_acc[mi][n8]);
      }
    }
    __syncthreads();
  }

#pragma unroll
  for (int mi = 0; mi < 2; ++mi) {
#pragma unroll
    for (int r = 0; r < 4; ++r) {
      float inv = 1.0f / lstate[mi][r];
      int row = q0 + wid * 32 + mi * 16 + ((lane >> 4) << 2) + r;
#pragma unroll
      for (int n8 = 0; n8 < 8; ++n8)
        Ob[(size_t)row * 4096 + h * 128 + n8 * 16 + (lane & 15)] =
            f2bf(o_acc[mi][n8][r] * inv);
    }
  }
}

// ---------------------------------------------------------------------------
// GEMM 2 (m97 structure): out[m][n] = sum_k Ob[m][k] * Wo[n][k], fp32 out.
// ---------------------------------------------------------------------------
__global__ __launch_bounds__(256, 2)
void gemm_out_bf16(const unsigned short* __restrict__ Ab,
                   const unsigned short* __restrict__ Wob,
                   float* __restrict__ Cout) {
  const int K = 4096;
  __shared__ __align__(16) unsigned short As[128][64];
  __shared__ __align__(16) unsigned short Bs[128][64];
  const int tid = threadIdx.x, lane = tid & 63, wid = tid >> 6;
  const int m0 = blockIdx.y * 128;
  const int n0 = blockIdx.x * 128;
  const unsigned short* Asrc = Ab + (size_t)m0 * K;
  const unsigned short* Bsrc = Wob + (size_t)n0 * K;

  f32x4 acc[4][4];
#pragma unroll
  for (int i = 0; i < 4; ++i)
#pragma unroll
    for (int j = 0; j < 4; ++j) acc[i][j] = (f32x4){0.f, 0.f, 0.f, 0.f};

  const int wm = (wid >> 1) * 64, wn = (wid & 1) * 64;
  const int srow = wid * 32 + (lane >> 3);
  const int scol = (lane & 7) * 8;

  for (int k0 = 0; k0 < K; k0 += 64) {
#pragma unroll
    for (int i = 0; i < 4; ++i) {
      gl2lds16(Asrc + (size_t)(srow + i * 8) * K + k0 + scol, &As[wid * 32 + i * 8][0]);
      gl2lds16(Bsrc + (size_t)(srow + i * 8) * K + k0 + scol, &Bs[wid * 32 + i * 8][0]);
    }
    __syncthreads();
#pragma unroll
    for (int ks = 0; ks < 2; ++ks) {
      short8 af[4], bfr[4];
      const int co = ks * 64 + ((lane >> 4) << 4);
#pragma unroll
      for (int i = 0; i < 4; ++i) {
        af[i]  = *(const short8*)((const char*)(&As[wm + i * 16 + (lane & 15)][0]) + co);
        bfr[i] = *(const short8*)((const char*)(&Bs[wn + i * 16 + (lane & 15)][0]) + co);
      }
#pragma unroll
      for (int i = 0; i < 4; ++i)
#pragma unroll
        for (int j = 0; j < 4; ++j)
          acc[i][j] = mfma16(af[i], bfr[j], acc[i][j]);
    }
    __syncthreads();
  }

#pragma unroll
  for (int i = 0; i < 4; ++i) {
    int rb = m0 + wm + i * 16 + ((lane >> 4) << 2);
#pragma unroll
    for (int j = 0; j < 4; ++j) {
      int cb = n0 + wn + j * 16 + (lane & 15);
#pragma unroll
      for (int r = 0; r < 4; ++r)
        Cout[(size_t)(rb + r) * 4096 + cb] = acc[i][j][r];
    }
  }
}

extern "C" void kernel_launch(void* const* d_in, const int* in_sizes, int n_in,
                              void* d_out, int out_size, void* d_ws, size_t ws_size,
                              hipStream_t stream) {
  const float* hs = (const float*)d_in[0];
  const float* Wq = (const float*)d_in[1];
  const float* Wk = (const float*)d_in[2];
  const float* Wv = (const float*)d_in[3];
  const float* Wo = (const float*)d_in[4];
  const int* pos = (const int*)d_in[7];

  // bf16 workspace layout (element offsets)
  unsigned short* hsb = (unsigned short*)d_ws;              // 8M
  unsigned short* Wqb = hsb + (size_t)8  * 1024 * 1024;     // 16M
  unsigned short* Wkb = Wqb + (size_t)16 * 1024 * 1024;     // 4M
  unsigned short* Wvb = Wkb + (size_t)4  * 1024 * 1024;     // 4M
  unsigned short* Wob = Wvb + (size_t)4  * 1024 * 1024;     // 16M
  unsigned short* Qb  = Wob + (size_t)16 * 1024 * 1024;     // 8M
  unsigned short* Kb  = Qb  + (size_t)8  * 1024 * 1024;     // 2M
  unsigned short* Vb  = Kb  + (size_t)2  * 1024 * 1024;     // 2M
  unsigned short* Ob  = Vb  + (size_t)2  * 1024 * 1024;     // 8M
  float* out = (float*)d_out;

  cvt_kernel<<<dim3(2048), 256, 0, stream>>>(hs, hsb, 2 * 1024 * 1024);
  cvt_kernel<<<dim3(2048), 256, 0, stream>>>(Wq, Wqb, 4 * 1024 * 1024);
  cvt_kernel<<<dim3(1024), 256, 0, stream>>>(Wk, Wkb, 1 * 1024 * 1024);
  cvt_kernel<<<dim3(1024), 256, 0, stream>>>(Wv, Wvb, 1 * 1024 * 1024);
  cvt_kernel<<<dim3(2048), 256, 0, stream>>>(Wo, Wob, 4 * 1024 * 1024);

  gemm_qkv_bf16<<<dim3(48, 16), 256, 0, stream>>>(hsb, Wqb, Wkb, Wvb, Qb, Kb, Vb);
  const int npairs = 2048 * 32 * 64 + 2048 * 8 * 64;
  rope_kernel<<<dim3((npairs + 255) / 256), 256, 0, stream>>>(Qb, Kb, pos);
  attn_kernel<<<dim3(16, 32), 256, 0, stream>>>(Qb, Kb, Vb, Ob);
  gemm_out_bf16<<<dim3(32, 16), 256, 0, stream>>>(Ob, Wob, out);
}

// Round 7
// 380.489 us; speedup vs baseline: 2.0975x; 1.5214x over previous
//
#include <hip/hip_runtime.h>

// Fused GQA prefill: cvt(fp32->bf16) -> QKV proj -> V-transpose -> RoPE ->
// causal flash attn (8-wave, balanced) -> O proj.
// B=1, T=2048, HID=4096, H=32, HKV=8, DH=128, pos=0.

#define DEVI __device__ __forceinline__

typedef __attribute__((ext_vector_type(8))) short short8;
typedef __attribute__((ext_vector_type(4))) float f32x4;

DEVI unsigned short f2bf(float f) {
  union { float f; unsigned u; } x; x.f = f;
  unsigned r = x.u + 0x7FFFu + ((x.u >> 16) & 1u);
  return (unsigned short)(r >> 16);
}
DEVI float bf2f(unsigned short h) {
  union { unsigned u; float f; } x; x.u = ((unsigned)h) << 16;
  return x.f;
}
DEVI f32x4 mfma16(short8 a, short8 b, f32x4 c) {
  return __builtin_amdgcn_mfma_f32_16x16x32_bf16(a, b, c, 0, 0, 0);
}
DEVI void gl2lds16(const unsigned short* g, unsigned short* l) {
  __builtin_amdgcn_global_load_lds(
      (const __attribute__((address_space(1))) unsigned int*)g,
      (__attribute__((address_space(3))) unsigned int*)l, 16, 0, 0);
}

// ---------------------------------------------------------------------------
// fp32 -> bf16 conversion
// ---------------------------------------------------------------------------
__global__ __launch_bounds__(256)
void cvt_kernel(const float* __restrict__ src, unsigned short* __restrict__ dst,
                int n4) {
  int i = blockIdx.x * 256 + threadIdx.x;
  const int stride = gridDim.x * 256;
  for (; i < n4; i += stride) {
    float4 v = ((const float4*)src)[i];
    ushort4 h;
    h.x = f2bf(v.x); h.y = f2bf(v.y); h.z = f2bf(v.z); h.w = f2bf(v.w);
    ((ushort4*)dst)[i] = h;
  }
}

// ---------------------------------------------------------------------------
// GEMM 1 (m97 structure): QKV projection, bf16 out.
// ---------------------------------------------------------------------------
__global__ __launch_bounds__(256, 2)
void gemm_qkv_bf16(const unsigned short* __restrict__ hsb,
                   const unsigned short* __restrict__ Wqb,
                   const unsigned short* __restrict__ Wkb,
                   const unsigned short* __restrict__ Wvb,
                   unsigned short* __restrict__ Qb,
                   unsigned short* __restrict__ Kb,
                   unsigned short* __restrict__ Vb) {
  const int K = 4096;
  __shared__ __align__(16) unsigned short As[128][64];
  __shared__ __align__(16) unsigned short Bs[128][64];
  const int tid = threadIdx.x, lane = tid & 63, wid = tid >> 6;
  const int m0 = blockIdx.y * 128;
  const int n0g = blockIdx.x * 128;

  const unsigned short* Bsrc; unsigned short* outp; int ldo, oc;
  if (n0g < 4096)      { Bsrc = Wqb + (size_t)n0g * K;          outp = Qb; ldo = 4096; oc = n0g; }
  else if (n0g < 5120) { Bsrc = Wkb + (size_t)(n0g - 4096) * K; outp = Kb; ldo = 1024; oc = n0g - 4096; }
  else                 { Bsrc = Wvb + (size_t)(n0g - 5120) * K; outp = Vb; ldo = 1024; oc = n0g - 5120; }
  const unsigned short* Asrc = hsb + (size_t)m0 * K;

  f32x4 acc[4][4];
#pragma unroll
  for (int i = 0; i < 4; ++i)
#pragma unroll
    for (int j = 0; j < 4; ++j) acc[i][j] = (f32x4){0.f, 0.f, 0.f, 0.f};

  const int wm = (wid >> 1) * 64, wn = (wid & 1) * 64;
  const int srow = wid * 32 + (lane >> 3);
  const int scol = (lane & 7) * 8;

  for (int k0 = 0; k0 < K; k0 += 64) {
#pragma unroll
    for (int i = 0; i < 4; ++i) {
      gl2lds16(Asrc + (size_t)(srow + i * 8) * K + k0 + scol, &As[wid * 32 + i * 8][0]);
      gl2lds16(Bsrc + (size_t)(srow + i * 8) * K + k0 + scol, &Bs[wid * 32 + i * 8][0]);
    }
    __syncthreads();
#pragma unroll
    for (int ks = 0; ks < 2; ++ks) {
      short8 af[4], bfr[4];
      const int co = ks * 64 + ((lane >> 4) << 4);
#pragma unroll
      for (int i = 0; i < 4; ++i) {
        af[i]  = *(const short8*)((const char*)(&As[wm + i * 16 + (lane & 15)][0]) + co);
        bfr[i] = *(const short8*)((const char*)(&Bs[wn + i * 16 + (lane & 15)][0]) + co);
      }
#pragma unroll
      for (int i = 0; i < 4; ++i)
#pragma unroll
        for (int j = 0; j < 4; ++j)
          acc[i][j] = mfma16(af[i], bfr[j], acc[i][j]);
    }
    __syncthreads();
  }

#pragma unroll
  for (int i = 0; i < 4; ++i) {
    int rb = m0 + wm + i * 16 + ((lane >> 4) << 2);
#pragma unroll
    for (int j = 0; j < 4; ++j) {
      int cb = oc + wn + j * 16 + (lane & 15);
#pragma unroll
      for (int r = 0; r < 4; ++r)
        outp[(size_t)(rb + r) * ldo + cb] = f2bf(acc[i][j][r]);
    }
  }
}

// ---------------------------------------------------------------------------
// V transpose: Vb [2048][1024] -> VtG [1024][2048]  (LDS tile transpose)
// ---------------------------------------------------------------------------
__global__ __launch_bounds__(256)
void transpose_v(const unsigned short* __restrict__ Vb,
                 unsigned short* __restrict__ VtG) {
  __shared__ unsigned short tile[64][68];
  const int tid = threadIdx.x;
  const int t0 = blockIdx.x * 64;   // time dim
  const int c0 = blockIdx.y * 64;   // channel dim
  const int r = tid >> 4;           // 0..15
  const int c4 = (tid & 15) << 2;   // 0..60
#pragma unroll
  for (int i = 0; i < 4; ++i) {
    ushort4 v = *(const ushort4*)(Vb + (size_t)(t0 + r + i * 16) * 1024 + c0 + c4);
    *(ushort4*)&tile[r + i * 16][c4] = v;
  }
  __syncthreads();
#pragma unroll
  for (int i = 0; i < 4; ++i) {
    int d = r + i * 16;
    ushort4 o;
    o.x = tile[c4 + 0][d]; o.y = tile[c4 + 1][d];
    o.z = tile[c4 + 2][d]; o.w = tile[c4 + 3][d];
    *(ushort4*)(VtG + (size_t)(c0 + d) * 2048 + t0 + c4) = o;
  }
}

// ---------------------------------------------------------------------------
// RoPE in place on bf16 Q and K.
// ---------------------------------------------------------------------------
__global__ __launch_bounds__(256)
void rope_kernel(unsigned short* __restrict__ Qb, unsigned short* __restrict__ Kb,
                 const int* __restrict__ posp) {
  const int QP = 2048 * 32 * 64;
  const int KP = 2048 * 8 * 64;
  int idx = blockIdx.x * 256 + threadIdx.x;
  if (idx >= QP + KP) return;
  unsigned short* base; int t, hh, d, ld;
  if (idx < QP) {
    base = Qb; ld = 4096;
    t = idx >> 11; int rem = idx & 2047; hh = rem >> 6; d = rem & 63;
  } else {
    int j = idx - QP; base = Kb; ld = 1024;
    t = j >> 9; int rem = j & 511; hh = rem >> 6; d = rem & 63;
  }
  float freq = exp2f(-(float)d * 0.29580575880077f);  // 500000^(-2d/128)
  float ang = (float)(t + posp[0]) * freq;
  float s, c;
  __sincosf(ang, &s, &c);
  size_t i1 = (size_t)t * ld + hh * 128 + d;
  float x1 = bf2f(base[i1]), x2 = bf2f(base[i1 + 64]);
  base[i1]      = f2bf(x1 * c - x2 * s);
  base[i1 + 64] = f2bf(x1 * s + x2 * c);
}

// ---------------------------------------------------------------------------
// Causal GQA flash attention. 512 threads = 8 waves x 16 q-rows (QBLK=128).
// KV tile 64. K and V^T staged via global_load_lds with pre-swizzled source.
// Complementary qt pairing balances per-CU work.
// ---------------------------------------------------------------------------
__global__ __launch_bounds__(512, 4)
void attn_kernel(const unsigned short* __restrict__ Qb,
                 const unsigned short* __restrict__ Kb,
                 const unsigned short* __restrict__ VtG,
                 unsigned short* __restrict__ Ob) {
  __shared__ __align__(16) unsigned short Ks[64][128];   // [s][d], swz ^((s&7)<<4)
  __shared__ __align__(16) unsigned short Vt[128][64];   // [d][s], swz ^((d&7)<<4)
  __shared__ __align__(16) unsigned short Ps[8][16][64]; // per-wave P, swz ^(((row>>2)&3)<<5)
  const int tid = threadIdx.x, lane = tid & 63, w = tid >> 6;
  const int h = blockIdx.y;
  const int qt = (blockIdx.y >> 4) ? (15 - blockIdx.x) : blockIdx.x;  // balance pairing
  const int kh = h >> 2;
  const int q0 = qt * 128;
  const float SCALE = 0.08838834764831845f;

  // Q fragments: wave w owns rows q0 + w*16 + (lane&15)
  short8 aq[4];
  {
    const int qrow = q0 + w * 16 + (lane & 15);
#pragma unroll
    for (int ks = 0; ks < 4; ++ks)
      aq[ks] = *(const short8*)(Qb + (size_t)qrow * 4096 + h * 128 + ks * 32 +
                                ((lane >> 4) << 3));
  }

  f32x4 o_acc[8];
#pragma unroll
  for (int n8 = 0; n8 < 8; ++n8) o_acc[n8] = (f32x4){0.f, 0.f, 0.f, 0.f};
  float mst[4], lst[4];
#pragma unroll
  for (int r = 0; r < 4; ++r) { mst[r] = -1e30f; lst[r] = 0.f; }

  // staging source offsets (pre-swizzled so linear LDS dest yields swizzled layout)
  const int ksrow0 = w * 8 + (lane >> 4);            // +0 / +4
  const int vdrow0 = w * 16 + (lane >> 3);           // +0 / +8

  const int ntiles = 2 * (qt + 1);
  for (int st = 0; st < ntiles; ++st) {
    const int s0 = st * 64;
    // stage K: wave w covers rows w*8 .. w*8+7 (two 1KB chunks)
#pragma unroll
    for (int j = 0; j < 2; ++j) {
      int sr = ksrow0 + j * 4;
      int sc = (((lane & 15) << 4) ^ ((sr & 7) << 4)) >> 1;
      gl2lds16(Kb + (size_t)(s0 + sr) * 1024 + kh * 128 + sc, &Ks[w * 8 + j * 4][0]);
    }
    // stage V^T: wave w covers rows w*16 .. w*16+15 (two 1KB chunks)
#pragma unroll
    for (int j = 0; j < 2; ++j) {
      int dr = vdrow0 + j * 8;
      int sc = (((lane & 7) << 4) ^ ((dr & 7) << 4)) >> 1;
      gl2lds16(VtG + (size_t)(kh * 128 + dr) * 2048 + s0 + sc, &Vt[w * 16 + j * 8][0]);
    }
    __syncthreads();

    // S = Q K^T (16 q-rows x 64 keys per wave)
    f32x4 sacc[4];
#pragma unroll
    for (int ni = 0; ni < 4; ++ni) sacc[ni] = (f32x4){0.f, 0.f, 0.f, 0.f};
#pragma unroll
    for (int ks = 0; ks < 4; ++ks) {
      const int co = ks * 64 + ((lane >> 4) << 4);
      short8 bk[4];
#pragma unroll
      for (int ni = 0; ni < 4; ++ni) {
        int kr = ni * 16 + (lane & 15);
        bk[ni] = *(const short8*)((const char*)(&Ks[kr][0]) + (co ^ ((kr & 7) << 4)));
      }
#pragma unroll
      for (int ni = 0; ni < 4; ++ni)
        sacc[ni] = mfma16(aq[ks], bk[ni], sacc[ni]);
    }

    // online softmax; write P to this wave's LDS region
    char* pb = (char*)(&Ps[w][0][0]);
#pragma unroll
    for (int r = 0; r < 4; ++r) {
      const int qrow = q0 + w * 16 + ((lane >> 4) << 2) + r;
      float v4[4]; float vmax = -1e30f;
#pragma unroll
      for (int ni = 0; ni < 4; ++ni) {
        int scol = s0 + ni * 16 + (lane & 15);
        float x = sacc[ni][r] * SCALE;
        if (scol > qrow) x = -1e30f;
        v4[ni] = x; vmax = fmaxf(vmax, x);
      }
      vmax = fmaxf(vmax, __shfl_xor(vmax, 1));
      vmax = fmaxf(vmax, __shfl_xor(vmax, 2));
      vmax = fmaxf(vmax, __shfl_xor(vmax, 4));
      vmax = fmaxf(vmax, __shfl_xor(vmax, 8));
      float mo = mst[r];
      float mn = fmaxf(mo, vmax);
      float al = __expf(mo - mn);
      float rs = 0.f;
      const int prow = ((lane >> 4) << 2) + r;
      const int pswz = ((prow >> 2) & 3) << 5;
#pragma unroll
      for (int ni = 0; ni < 4; ++ni) {
        float p = __expf(v4[ni] - mn);
        rs += p;
        int cbyte = (ni * 16 + (lane & 15)) * 2;
        *(unsigned short*)(pb + prow * 128 + (cbyte ^ pswz)) = f2bf(p);
      }
      rs += __shfl_xor(rs, 1);
      rs += __shfl_xor(rs, 2);
      rs += __shfl_xor(rs, 4);
      rs += __shfl_xor(rs, 8);
      lst[r] = lst[r] * al + rs;
      mst[r] = mn;
#pragma unroll
      for (int n8 = 0; n8 < 8; ++n8) o_acc[n8][r] *= al;
    }

    // O += P V
#pragma unroll
    for (int ks2 = 0; ks2 < 2; ++ks2) {
      const int co = ks2 * 64 + ((lane >> 4) << 4);
      const int pr = lane & 15;
      short8 pa = *(const short8*)(pb + pr * 128 + (co ^ (((pr >> 2) & 3) << 5)));
#pragma unroll
      for (int n8 = 0; n8 < 8; ++n8) {
        int vr = n8 * 16 + (lane & 15);
        short8 bv = *(const short8*)((const char*)(&Vt[vr][0]) + (co ^ ((vr & 7) << 4)));
        o_acc[n8] = mfma16(pa, bv, o_acc[n8]);
      }
    }
    __syncthreads();
  }

  // epilogue
#pragma unroll
  for (int r = 0; r < 4; ++r) {
    float inv = 1.0f / lst[r];
    int row = q0 + w * 16 + ((lane >> 4) << 2) + r;
#pragma unroll
    for (int n8 = 0; n8 < 8; ++n8)
      Ob[(size_t)row * 4096 + h * 128 + n8 * 16 + (lane & 15)] =
          f2bf(o_acc[n8][r] * inv);
  }
}

// ---------------------------------------------------------------------------
// GEMM 2 (m97 structure): O projection, fp32 out.
// ---------------------------------------------------------------------------
__global__ __launch_bounds__(256, 2)
void gemm_out_bf16(const unsigned short* __restrict__ Ab,
                   const unsigned short* __restrict__ Wob,
                   float* __restrict__ Cout) {
  const int K = 4096;
  __shared__ __align__(16) unsigned short As[128][64];
  __shared__ __align__(16) unsigned short Bs[128][64];
  const int tid = threadIdx.x, lane = tid & 63, wid = tid >> 6;
  const int m0 = blockIdx.y * 128;
  const int n0 = blockIdx.x * 128;
  const unsigned short* Asrc = Ab + (size_t)m0 * K;
  const unsigned short* Bsrc = Wob + (size_t)n0 * K;

  f32x4 acc[4][4];
#pragma unroll
  for (int i = 0; i < 4; ++i)
#pragma unroll
    for (int j = 0; j < 4; ++j) acc[i][j] = (f32x4){0.f, 0.f, 0.f, 0.f};

  const int wm = (wid >> 1) * 64, wn = (wid & 1) * 64;
  const int srow = wid * 32 + (lane >> 3);
  const int scol = (lane & 7) * 8;

  for (int k0 = 0; k0 < K; k0 += 64) {
#pragma unroll
    for (int i = 0; i < 4; ++i) {
      gl2lds16(Asrc + (size_t)(srow + i * 8) * K + k0 + scol, &As[wid * 32 + i * 8][0]);
      gl2lds16(Bsrc + (size_t)(srow + i * 8) * K + k0 + scol, &Bs[wid * 32 + i * 8][0]);
    }
    __syncthreads();
#pragma unroll
    for (int ks = 0; ks < 2; ++ks) {
      short8 af[4], bfr[4];
      const int co = ks * 64 + ((lane >> 4) << 4);
#pragma unroll
      for (int i = 0; i < 4; ++i) {
        af[i]  = *(const short8*)((const char*)(&As[wm + i * 16 + (lane & 15)][0]) + co);
        bfr[i] = *(const short8*)((const char*)(&Bs[wn + i * 16 + (lane & 15)][0]) + co);
      }
#pragma unroll
      for (int i = 0; i < 4; ++i)
#pragma unroll
        for (int j = 0; j < 4; ++j)
          acc[i][j] = mfma16(af[i], bfr[j], acc[i][j]);
    }
    __syncthreads();
  }

#pragma unroll
  for (int i = 0; i < 4; ++i) {
    int rb = m0 + wm + i * 16 + ((lane >> 4) << 2);
#pragma unroll
    for (int j = 0; j < 4; ++j) {
      int cb = n0 + wn + j * 16 + (lane & 15);
#pragma unroll
      for (int r = 0; r < 4; ++r)
        Cout[(size_t)(rb + r) * 4096 + cb] = acc[i][j][r];
    }
  }
}

extern "C" void kernel_launch(void* const* d_in, const int* in_sizes, int n_in,
                              void* d_out, int out_size, void* d_ws, size_t ws_size,
                              hipStream_t stream) {
  const float* hs = (const float*)d_in[0];
  const float* Wq = (const float*)d_in[1];
  const float* Wk = (const float*)d_in[2];
  const float* Wv = (const float*)d_in[3];
  const float* Wo = (const float*)d_in[4];
  const int* pos = (const int*)d_in[7];

  // bf16 workspace layout (element offsets)
  unsigned short* hsb = (unsigned short*)d_ws;              // 8M
  unsigned short* Wqb = hsb + (size_t)8  * 1024 * 1024;     // 16M
  unsigned short* Wkb = Wqb + (size_t)16 * 1024 * 1024;     // 4M
  unsigned short* Wvb = Wkb + (size_t)4  * 1024 * 1024;     // 4M
  unsigned short* Wob = Wvb + (size_t)4  * 1024 * 1024;     // 16M
  unsigned short* Qb  = Wob + (size_t)16 * 1024 * 1024;     // 8M
  unsigned short* Kb  = Qb  + (size_t)8  * 1024 * 1024;     // 2M
  unsigned short* Vb  = Kb  + (size_t)2  * 1024 * 1024;     // 2M
  unsigned short* Ob  = Vb  + (size_t)2  * 1024 * 1024;     // 8M
  // VtG (2M elems) aliases hsb: hsb is dead after gemm_qkv, rewritten by cvt
  // at the start of every call -> deterministic.
  unsigned short* VtG = hsb;
  float* out = (float*)d_out;

  cvt_kernel<<<dim3(2048), 256, 0, stream>>>(hs, hsb, 2 * 1024 * 1024);
  cvt_kernel<<<dim3(2048), 256, 0, stream>>>(Wq, Wqb, 4 * 1024 * 1024);
  cvt_kernel<<<dim3(1024), 256, 0, stream>>>(Wk, Wkb, 1 * 1024 * 1024);
  cvt_kernel<<<dim3(1024), 256, 0, stream>>>(Wv, Wvb, 1 * 1024 * 1024);
  cvt_kernel<<<dim3(2048), 256, 0, stream>>>(Wo, Wob, 4 * 1024 * 1024);

  gemm_qkv_bf16<<<dim3(48, 16), 256, 0, stream>>>(hsb, Wqb, Wkb, Wvb, Qb, Kb, Vb);
  transpose_v<<<dim3(32, 16), 256, 0, stream>>>(Vb, VtG);
  const int npairs = 2048 * 32 * 64 + 2048 * 8 * 64;
  rope_kernel<<<dim3((npairs + 255) / 256), 256, 0, stream>>>(Qb, Kb, pos);
  attn_kernel<<<dim3(16, 32), 512, 0, stream>>>(Qb, Kb, VtG, Ob);
  gemm_out_bf16<<<dim3(32, 16), 256, 0, stream>>>(Ob, Wob, out);
}

// Round 8
// 367.402 us; speedup vs baseline: 2.1722x; 1.0356x over previous
//
#include <hip/hip_runtime.h>

// Fused GQA prefill: cvt(fp32->bf16) -> QKV proj (8-phase 256^2 template) ->
// V-transpose -> RoPE -> causal flash attn (8-wave, balanced) -> O proj (m97).
// B=1, T=2048, HID=4096, H=32, HKV=8, DH=128, pos=0.

#define DEVI __device__ __forceinline__

typedef __attribute__((ext_vector_type(8))) short short8;
typedef __attribute__((ext_vector_type(4))) float f32x4;

DEVI unsigned short f2bf(float f) {
  union { float f; unsigned u; } x; x.f = f;
  unsigned r = x.u + 0x7FFFu + ((x.u >> 16) & 1u);
  return (unsigned short)(r >> 16);
}
DEVI float bf2f(unsigned short h) {
  union { unsigned u; float f; } x; x.u = ((unsigned)h) << 16;
  return x.f;
}
DEVI f32x4 mfma16(short8 a, short8 b, f32x4 c) {
  return __builtin_amdgcn_mfma_f32_16x16x32_bf16(a, b, c, 0, 0, 0);
}
DEVI void gl2lds16(const unsigned short* g, unsigned short* l) {
  __builtin_amdgcn_global_load_lds(
      (const __attribute__((address_space(1))) unsigned int*)g,
      (__attribute__((address_space(3))) unsigned int*)l, 16, 0, 0);
}
DEVI void bar() { __builtin_amdgcn_s_barrier(); }
DEVI void sfence() { __builtin_amdgcn_sched_barrier(0); }

// ---------------------------------------------------------------------------
// fp32 -> bf16 conversion
// ---------------------------------------------------------------------------
__global__ __launch_bounds__(256)
void cvt_kernel(const float* __restrict__ src, unsigned short* __restrict__ dst,
                int n4) {
  int i = blockIdx.x * 256 + threadIdx.x;
  const int stride = gridDim.x * 256;
  for (; i < n4; i += stride) {
    float4 v = ((const float4*)src)[i];
    ushort4 h;
    h.x = f2bf(v.x); h.y = f2bf(v.y); h.z = f2bf(v.z); h.w = f2bf(v.w);
    ((ushort4*)dst)[i] = h;
  }
}

// ---------------------------------------------------------------------------
// GEMM 1: QKV projection, 8-phase 256x256 template (T2+T3+T4+T5).
// C[m][n] = sum_k hs[m][k] * W[n][k]; n-tile selects Wq/Wk/Wv. Output bf16.
// 512 thr = 8 waves (2 M x 4 N), per-wave 128x64, BK=64.
// LDS [buf][A/B][kh][256][32] bf16, chunk-XOR swizzle c^((row>>1)&3).
// Per K-tile: 4 phases (kh x mq), 16 MFMA each; 1 stage-unit (2 gl2lds) per
// phase at prefetch distance 2; vmcnt(6) once per K-tile (counted, never 0
// until the epilogue drain).
// ---------------------------------------------------------------------------
__global__ __launch_bounds__(512, 2)
void gemm_qkv_8ph(const unsigned short* __restrict__ hsb,
                  const unsigned short* __restrict__ Wqb,
                  const unsigned short* __restrict__ Wkb,
                  const unsigned short* __restrict__ Wvb,
                  unsigned short* __restrict__ Qb,
                  unsigned short* __restrict__ Kb,
                  unsigned short* __restrict__ Vb) {
  const int K = 4096;
  const int NT = 64;  // K / 64
  __shared__ __align__(16) unsigned short Ls[2][2][2][256][32]; // 128 KiB
  const int tid = threadIdx.x, lane = tid & 63, w = tid >> 6;
  const int wr = w >> 2, wc = w & 3;
  const int m0 = blockIdx.y * 256;
  const int n0g = blockIdx.x * 256;

  const unsigned short* Bsrc; unsigned short* outp; int ldo, oc;
  if (n0g < 4096)      { Bsrc = Wqb + (size_t)n0g * K;          outp = Qb; ldo = 4096; oc = n0g; }
  else if (n0g < 5120) { Bsrc = Wkb + (size_t)(n0g - 4096) * K; outp = Kb; ldo = 1024; oc = n0g - 4096; }
  else                 { Bsrc = Wvb + (size_t)(n0g - 5120) * K; outp = Vb; ldo = 1024; oc = n0g - 5120; }
  const unsigned short* Asrc = hsb + (size_t)m0 * K;

  // stage one 16KB unit (ab: 0=A,1=B; kh half; tile tt; buffer bb)
  auto stageU = [&](const unsigned short* src, int ab, int kh, int tt, int bb) {
#pragma unroll
    for (int j = 0; j < 2; ++j) {
      const int seg = j * 8 + w;                // 0..15 (wave-uniform)
      const int row = seg * 16 + (lane >> 2);   // 0..255
      const int cs  = (lane & 3) ^ ((row >> 1) & 3);
      gl2lds16(src + (size_t)row * K + tt * 64 + kh * 32 + cs * 8,
               &Ls[bb][ab][kh][seg * 16][0]);
    }
  };
  auto ldA = [&](int bb, int kh, int fm) -> short8 {
    const int ra = wr * 128 + fm * 16 + (lane & 15);
    const int cs = (lane >> 4) ^ ((ra >> 1) & 3);
    return *(const short8*)&Ls[bb][0][kh][ra][cs * 8];
  };
  auto ldB = [&](int bb, int kh, int fn) -> short8 {
    const int rb = wc * 64 + fn * 16 + (lane & 15);
    const int cs = (lane >> 4) ^ ((rb >> 1) & 3);
    return *(const short8*)&Ls[bb][1][kh][rb][cs * 8];
  };

  f32x4 acc[8][4];
#pragma unroll
  for (int i = 0; i < 8; ++i)
#pragma unroll
    for (int j = 0; j < 4; ++j) acc[i][j] = (f32x4){0.f, 0.f, 0.f, 0.f};

  // Prologue: tile0 fully (A kh0, A kh1, B kh0, B kh1) then tile1's first 3
  // units (B kh0, A kh0, B kh1). vmcnt(6) -> tile0 landed, 3 units in flight.
  stageU(Asrc, 0, 0, 0, 0);
  stageU(Asrc, 0, 1, 0, 0);
  stageU(Bsrc, 1, 0, 0, 0);
  stageU(Bsrc, 1, 1, 0, 0);
  stageU(Bsrc, 1, 0, 1, 1);
  stageU(Asrc, 0, 0, 1, 1);
  stageU(Bsrc, 1, 1, 1, 1);
  asm volatile("s_waitcnt vmcnt(6)" ::: "memory");
  bar();
  sfence();

  short8 af[4], bfr[4];
  for (int t = 0; t < NT; ++t) {
    const int bb = t & 1, nb = bb ^ 1;
    // ---- P1: (kh0, mq0); stage A(t+1)-kh1 -> nb ----
#pragma unroll
    for (int i = 0; i < 4; ++i) af[i] = ldA(bb, 0, i);
#pragma unroll
    for (int i = 0; i < 4; ++i) bfr[i] = ldB(bb, 0, i);
    if (t + 1 < NT) stageU(Asrc, 0, 1, t + 1, nb);
    bar();
    __builtin_amdgcn_s_setprio(1);
#pragma unroll
    for (int i = 0; i < 4; ++i)
#pragma unroll
      for (int j = 0; j < 4; ++j) acc[i][j] = mfma16(af[i], bfr[j], acc[i][j]);
    __builtin_amdgcn_s_setprio(0);
    sfence(); bar(); sfence();
    // ---- P2: (kh0, mq1); stage B(t+2)-kh0 -> bb ----
#pragma unroll
    for (int i = 0; i < 4; ++i) af[i] = ldA(bb, 0, 4 + i);
    if (t + 2 < NT) stageU(Bsrc, 1, 0, t + 2, bb);
    bar();
    __builtin_amdgcn_s_setprio(1);
#pragma unroll
    for (int i = 0; i < 4; ++i)
#pragma unroll
      for (int j = 0; j < 4; ++j) acc[4 + i][j] = mfma16(af[i], bfr[j], acc[4 + i][j]);
    __builtin_amdgcn_s_setprio(0);
    sfence(); bar(); sfence();
    // ---- P3: (kh1, mq0); stage A(t+2)-kh0 -> bb ----
#pragma unroll
    for (int i = 0; i < 4; ++i) af[i] = ldA(bb, 1, i);
#pragma unroll
    for (int i = 0; i < 4; ++i) bfr[i] = ldB(bb, 1, i);
    if (t + 2 < NT) stageU(Asrc, 0, 0, t + 2, bb);
    bar();
    __builtin_amdgcn_s_setprio(1);
#pragma unroll
    for (int i = 0; i < 4; ++i)
#pragma unroll
      for (int j = 0; j < 4; ++j) acc[i][j] = mfma16(af[i], bfr[j], acc[i][j]);
    __builtin_amdgcn_s_setprio(0);
    sfence(); bar(); sfence();
    // ---- P4: (kh1, mq1); stage B(t+2)-kh1 -> bb; counted vmcnt ----
#pragma unroll
    for (int i = 0; i < 4; ++i) af[i] = ldA(bb, 1, 4 + i);
    if (t + 2 < NT) stageU(Bsrc, 1, 1, t + 2, bb);
    bar();
    __builtin_amdgcn_s_setprio(1);
#pragma unroll
    for (int i = 0; i < 4; ++i)
#pragma unroll
      for (int j = 0; j < 4; ++j) acc[4 + i][j] = mfma16(af[i], bfr[j], acc[4 + i][j]);
    __builtin_amdgcn_s_setprio(0);
    if (t < NT - 2) asm volatile("s_waitcnt vmcnt(6)" ::: "memory");
    else            asm volatile("s_waitcnt vmcnt(0)" ::: "memory");
    sfence(); bar(); sfence();
  }

  // epilogue: bf16 store
#pragma unroll
  for (int fm = 0; fm < 8; ++fm) {
    const int rb0 = m0 + wr * 128 + fm * 16 + ((lane >> 4) << 2);
#pragma unroll
    for (int fn = 0; fn < 4; ++fn) {
      const int cb = oc + wc * 64 + fn * 16 + (lane & 15);
#pragma unroll
      for (int r = 0; r < 4; ++r)
        outp[(size_t)(rb0 + r) * ldo + cb] = f2bf(acc[fm][fn][r]);
    }
  }
}

// ---------------------------------------------------------------------------
// V transpose: Vb [2048][1024] -> VtG [1024][2048]  (LDS tile transpose)
// ---------------------------------------------------------------------------
__global__ __launch_bounds__(256)
void transpose_v(const unsigned short* __restrict__ Vb,
                 unsigned short* __restrict__ VtG) {
  __shared__ unsigned short tile[64][68];
  const int tid = threadIdx.x;
  const int t0 = blockIdx.x * 64;
  const int c0 = blockIdx.y * 64;
  const int r = tid >> 4;
  const int c4 = (tid & 15) << 2;
#pragma unroll
  for (int i = 0; i < 4; ++i) {
    ushort4 v = *(const ushort4*)(Vb + (size_t)(t0 + r + i * 16) * 1024 + c0 + c4);
    *(ushort4*)&tile[r + i * 16][c4] = v;
  }
  __syncthreads();
#pragma unroll
  for (int i = 0; i < 4; ++i) {
    int d = r + i * 16;
    ushort4 o;
    o.x = tile[c4 + 0][d]; o.y = tile[c4 + 1][d];
    o.z = tile[c4 + 2][d]; o.w = tile[c4 + 3][d];
    *(ushort4*)(VtG + (size_t)(c0 + d) * 2048 + t0 + c4) = o;
  }
}

// ---------------------------------------------------------------------------
// RoPE in place on bf16 Q and K.
// ---------------------------------------------------------------------------
__global__ __launch_bounds__(256)
void rope_kernel(unsigned short* __restrict__ Qb, unsigned short* __restrict__ Kb,
                 const int* __restrict__ posp) {
  const int QP = 2048 * 32 * 64;
  const int KP = 2048 * 8 * 64;
  int idx = blockIdx.x * 256 + threadIdx.x;
  if (idx >= QP + KP) return;
  unsigned short* base; int t, hh, d, ld;
  if (idx < QP) {
    base = Qb; ld = 4096;
    t = idx >> 11; int rem = idx & 2047; hh = rem >> 6; d = rem & 63;
  } else {
    int j = idx - QP; base = Kb; ld = 1024;
    t = j >> 9; int rem = j & 511; hh = rem >> 6; d = rem & 63;
  }
  float freq = exp2f(-(float)d * 0.29580575880077f);  // 500000^(-2d/128)
  float ang = (float)(t + posp[0]) * freq;
  float s, c;
  __sincosf(ang, &s, &c);
  size_t i1 = (size_t)t * ld + hh * 128 + d;
  float x1 = bf2f(base[i1]), x2 = bf2f(base[i1 + 64]);
  base[i1]      = f2bf(x1 * c - x2 * s);
  base[i1 + 64] = f2bf(x1 * s + x2 * c);
}

// ---------------------------------------------------------------------------
// Causal GQA flash attention. 512 threads = 8 waves x 16 q-rows (QBLK=128).
// ---------------------------------------------------------------------------
__global__ __launch_bounds__(512, 4)
void attn_kernel(const unsigned short* __restrict__ Qb,
                 const unsigned short* __restrict__ Kb,
                 const unsigned short* __restrict__ VtG,
                 unsigned short* __restrict__ Ob) {
  __shared__ __align__(16) unsigned short Ks[64][128];
  __shared__ __align__(16) unsigned short Vt[128][64];
  __shared__ __align__(16) unsigned short Ps[8][16][64];
  const int tid = threadIdx.x, lane = tid & 63, w = tid >> 6;
  const int h = blockIdx.y;
  const int qt = (blockIdx.y >> 4) ? (15 - blockIdx.x) : blockIdx.x;
  const int kh = h >> 2;
  const int q0 = qt * 128;
  const float SCALE = 0.08838834764831845f;

  short8 aq[4];
  {
    const int qrow = q0 + w * 16 + (lane & 15);
#pragma unroll
    for (int ks = 0; ks < 4; ++ks)
      aq[ks] = *(const short8*)(Qb + (size_t)qrow * 4096 + h * 128 + ks * 32 +
                                ((lane >> 4) << 3));
  }

  f32x4 o_acc[8];
#pragma unroll
  for (int n8 = 0; n8 < 8; ++n8) o_acc[n8] = (f32x4){0.f, 0.f, 0.f, 0.f};
  float mst[4], lst[4];
#pragma unroll
  for (int r = 0; r < 4; ++r) { mst[r] = -1e30f; lst[r] = 0.f; }

  const int ksrow0 = w * 8 + (lane >> 4);
  const int vdrow0 = w * 16 + (lane >> 3);

  const int ntiles = 2 * (qt + 1);
  for (int st = 0; st < ntiles; ++st) {
    const int s0 = st * 64;
#pragma unroll
    for (int j = 0; j < 2; ++j) {
      int sr = ksrow0 + j * 4;
      int sc = (((lane & 15) << 4) ^ ((sr & 7) << 4)) >> 1;
      gl2lds16(Kb + (size_t)(s0 + sr) * 1024 + kh * 128 + sc, &Ks[w * 8 + j * 4][0]);
    }
#pragma unroll
    for (int j = 0; j < 2; ++j) {
      int dr = vdrow0 + j * 8;
      int sc = (((lane & 7) << 4) ^ ((dr & 7) << 4)) >> 1;
      gl2lds16(VtG + (size_t)(kh * 128 + dr) * 2048 + s0 + sc, &Vt[w * 16 + j * 8][0]);
    }
    __syncthreads();

    f32x4 sacc[4];
#pragma unroll
    for (int ni = 0; ni < 4; ++ni) sacc[ni] = (f32x4){0.f, 0.f, 0.f, 0.f};
#pragma unroll
    for (int ks = 0; ks < 4; ++ks) {
      const int co = ks * 64 + ((lane >> 4) << 4);
      short8 bk[4];
#pragma unroll
      for (int ni = 0; ni < 4; ++ni) {
        int kr = ni * 16 + (lane & 15);
        bk[ni] = *(const short8*)((const char*)(&Ks[kr][0]) + (co ^ ((kr & 7) << 4)));
      }
#pragma unroll
      for (int ni = 0; ni < 4; ++ni)
        sacc[ni] = mfma16(aq[ks], bk[ni], sacc[ni]);
    }

    char* pb = (char*)(&Ps[w][0][0]);
#pragma unroll
    for (int r = 0; r < 4; ++r) {
      const int qrow = q0 + w * 16 + ((lane >> 4) << 2) + r;
      float v4[4]; float vmax = -1e30f;
#pragma unroll
      for (int ni = 0; ni < 4; ++ni) {
        int scol = s0 + ni * 16 + (lane & 15);
        float x = sacc[ni][r] * SCALE;
        if (scol > qrow) x = -1e30f;
        v4[ni] = x; vmax = fmaxf(vmax, x);
      }
      vmax = fmaxf(vmax, __shfl_xor(vmax, 1));
      vmax = fmaxf(vmax, __shfl_xor(vmax, 2));
      vmax = fmaxf(vmax, __shfl_xor(vmax, 4));
      vmax = fmaxf(vmax, __shfl_xor(vmax, 8));
      float mo = mst[r];
      float mn = fmaxf(mo, vmax);
      float al = __expf(mo - mn);
      float rs = 0.f;
      const int prow = ((lane >> 4) << 2) + r;
      const int pswz = ((prow >> 2) & 3) << 5;
#pragma unroll
      for (int ni = 0; ni < 4; ++ni) {
        float p = __expf(v4[ni] - mn);
        rs += p;
        int cbyte = (ni * 16 + (lane & 15)) * 2;
        *(unsigned short*)(pb + prow * 128 + (cbyte ^ pswz)) = f2bf(p);
      }
      rs += __shfl_xor(rs, 1);
      rs += __shfl_xor(rs, 2);
      rs += __shfl_xor(rs, 4);
      rs += __shfl_xor(rs, 8);
      lst[r] = lst[r] * al + rs;
      mst[r] = mn;
#pragma unroll
      for (int n8 = 0; n8 < 8; ++n8) o_acc[n8][r] *= al;
    }

#pragma unroll
    for (int ks2 = 0; ks2 < 2; ++ks2) {
      const int co = ks2 * 64 + ((lane >> 4) << 4);
      const int pr = lane & 15;
      short8 pa = *(const short8*)(pb + pr * 128 + (co ^ (((pr >> 2) & 3) << 5)));
#pragma unroll
      for (int n8 = 0; n8 < 8; ++n8) {
        int vr = n8 * 16 + (lane & 15);
        short8 bv = *(const short8*)((const char*)(&Vt[vr][0]) + (co ^ ((vr & 7) << 4)));
        o_acc[n8] = mfma16(pa, bv, o_acc[n8]);
      }
    }
    __syncthreads();
  }

#pragma unroll
  for (int r = 0; r < 4; ++r) {
    float inv = 1.0f / lst[r];
    int row = q0 + w * 16 + ((lane >> 4) << 2) + r;
#pragma unroll
    for (int n8 = 0; n8 < 8; ++n8)
      Ob[(size_t)row * 4096 + h * 128 + n8 * 16 + (lane & 15)] =
          f2bf(o_acc[n8][r] * inv);
  }
}

// ---------------------------------------------------------------------------
// GEMM 2 (m97 structure): O projection, fp32 out.
// ---------------------------------------------------------------------------
__global__ __launch_bounds__(256, 2)
void gemm_out_bf16(const unsigned short* __restrict__ Ab,
                   const unsigned short* __restrict__ Wob,
                   float* __restrict__ Cout) {
  const int K = 4096;
  __shared__ __align__(16) unsigned short As[128][64];
  __shared__ __align__(16) unsigned short Bs[128][64];
  const int tid = threadIdx.x, lane = tid & 63, wid = tid >> 6;
  const int m0 = blockIdx.y * 128;
  const int n0 = blockIdx.x * 128;
  const unsigned short* Asrc = Ab + (size_t)m0 * K;
  const unsigned short* Bsrc = Wob + (size_t)n0 * K;

  f32x4 acc[4][4];
#pragma unroll
  for (int i = 0; i < 4; ++i)
#pragma unroll
    for (int j = 0; j < 4; ++j) acc[i][j] = (f32x4){0.f, 0.f, 0.f, 0.f};

  const int wm = (wid >> 1) * 64, wn = (wid & 1) * 64;
  const int srow = wid * 32 + (lane >> 3);
  const int scol = (lane & 7) * 8;

  for (int k0 = 0; k0 < K; k0 += 64) {
#pragma unroll
    for (int i = 0; i < 4; ++i) {
      gl2lds16(Asrc + (size_t)(srow + i * 8) * K + k0 + scol, &As[wid * 32 + i * 8][0]);
      gl2lds16(Bsrc + (size_t)(srow + i * 8) * K + k0 + scol, &Bs[wid * 32 + i * 8][0]);
    }
    __syncthreads();
#pragma unroll
    for (int ks = 0; ks < 2; ++ks) {
      short8 af[4], bfr[4];
      const int co = ks * 64 + ((lane >> 4) << 4);
#pragma unroll
      for (int i = 0; i < 4; ++i) {
        af[i]  = *(const short8*)((const char*)(&As[wm + i * 16 + (lane & 15)][0]) + co);
        bfr[i] = *(const short8*)((const char*)(&Bs[wn + i * 16 + (lane & 15)][0]) + co);
      }
#pragma unroll
      for (int i = 0; i < 4; ++i)
#pragma unroll
        for (int j = 0; j < 4; ++j)
          acc[i][j] = mfma16(af[i], bfr[j], acc[i][j]);
    }
    __syncthreads();
  }

#pragma unroll
  for (int i = 0; i < 4; ++i) {
    int rb = m0 + wm + i * 16 + ((lane >> 4) << 2);
#pragma unroll
    for (int j = 0; j < 4; ++j) {
      int cb = n0 + wn + j * 16 + (lane & 15);
#pragma unroll
      for (int r = 0; r < 4; ++r)
        Cout[(size_t)(rb + r) * 4096 + cb] = acc[i][j][r];
    }
  }
}

extern "C" void kernel_launch(void* const* d_in, const int* in_sizes, int n_in,
                              void* d_out, int out_size, void* d_ws, size_t ws_size,
                              hipStream_t stream) {
  const float* hs = (const float*)d_in[0];
  const float* Wq = (const float*)d_in[1];
  const float* Wk = (const float*)d_in[2];
  const float* Wv = (const float*)d_in[3];
  const float* Wo = (const float*)d_in[4];
  const int* pos = (const int*)d_in[7];

  unsigned short* hsb = (unsigned short*)d_ws;              // 8M
  unsigned short* Wqb = hsb + (size_t)8  * 1024 * 1024;     // 16M
  unsigned short* Wkb = Wqb + (size_t)16 * 1024 * 1024;     // 4M
  unsigned short* Wvb = Wkb + (size_t)4  * 1024 * 1024;     // 4M
  unsigned short* Wob = Wvb + (size_t)4  * 1024 * 1024;     // 16M
  unsigned short* Qb  = Wob + (size_t)16 * 1024 * 1024;     // 8M
  unsigned short* Kb  = Qb  + (size_t)8  * 1024 * 1024;     // 2M
  unsigned short* Vb  = Kb  + (size_t)2  * 1024 * 1024;     // 2M
  unsigned short* Ob  = Vb  + (size_t)2  * 1024 * 1024;     // 8M
  unsigned short* VtG = hsb;  // aliases hsb (dead after QKV GEMM; cvt rewrites)
  float* out = (float*)d_out;

  cvt_kernel<<<dim3(2048), 256, 0, stream>>>(hs, hsb, 2 * 1024 * 1024);
  cvt_kernel<<<dim3(2048), 256, 0, stream>>>(Wq, Wqb, 4 * 1024 * 1024);
  cvt_kernel<<<dim3(1024), 256, 0, stream>>>(Wk, Wkb, 1 * 1024 * 1024);
  cvt_kernel<<<dim3(1024), 256, 0, stream>>>(Wv, Wvb, 1 * 1024 * 1024);
  cvt_kernel<<<dim3(2048), 256, 0, stream>>>(Wo, Wob, 4 * 1024 * 1024);

  gemm_qkv_8ph<<<dim3(24, 8), 512, 0, stream>>>(hsb, Wqb, Wkb, Wvb, Qb, Kb, Vb);
  transpose_v<<<dim3(32, 16), 256, 0, stream>>>(Vb, VtG);
  const int npairs = 2048 * 32 * 64 + 2048 * 8 * 64;
  rope_kernel<<<dim3((npairs + 255) / 256), 256, 0, stream>>>(Qb, Kb, pos);
  attn_kernel<<<dim3(16, 32), 512, 0, stream>>>(Qb, Kb, VtG, Ob);
  gemm_out_bf16<<<dim3(32, 16), 256, 0, stream>>>(Ob, Wob, out);
}

// Round 10
// 366.878 us; speedup vs baseline: 2.1753x; 1.0014x over previous
//
#include <hip/hip_runtime.h>

// Fused GQA prefill: cvt5(fp32->bf16, one launch) -> QKV proj (8-phase 256^2)
// -> postproc(V-transpose + RoPE, one launch) -> causal flash attn
// (8-wave, KVBLK=128, balanced) -> O proj (m97).
// B=1, T=2048, HID=4096, H=32, HKV=8, DH=128, pos=0.

#define DEVI __device__ __forceinline__

typedef __attribute__((ext_vector_type(8))) short short8;
typedef __attribute__((ext_vector_type(4))) float f32x4;

DEVI unsigned short f2bf(float f) {
  union { float f; unsigned u; } x; x.f = f;
  unsigned r = x.u + 0x7FFFu + ((x.u >> 16) & 1u);
  return (unsigned short)(r >> 16);
}
DEVI float bf2f(unsigned short h) {
  union { unsigned u; float f; } x; x.u = ((unsigned)h) << 16;
  return x.f;
}
DEVI f32x4 mfma16(short8 a, short8 b, f32x4 c) {
  return __builtin_amdgcn_mfma_f32_16x16x32_bf16(a, b, c, 0, 0, 0);
}
DEVI void gl2lds16(const unsigned short* g, unsigned short* l) {
  __builtin_amdgcn_global_load_lds(
      (const __attribute__((address_space(1))) unsigned int*)g,
      (__attribute__((address_space(3))) unsigned int*)l, 16, 0, 0);
}
DEVI void bar() { __builtin_amdgcn_s_barrier(); }
DEVI void sfence() { __builtin_amdgcn_sched_barrier(0); }

// ---------------------------------------------------------------------------
// One-launch fp32 -> bf16 conversion of all 5 tensors (grid-stride each).
// ---------------------------------------------------------------------------
DEVI void cvt_region(const float* __restrict__ src,
                     unsigned short* __restrict__ dst, int n4, int start,
                     int stride) {
  for (int i = start; i < n4; i += stride) {
    float4 v = ((const float4*)src)[i];
    ushort4 h;
    h.x = f2bf(v.x); h.y = f2bf(v.y); h.z = f2bf(v.z); h.w = f2bf(v.w);
    ((ushort4*)dst)[i] = h;
  }
}
__global__ __launch_bounds__(256)
void cvt5_kernel(const float* __restrict__ s0, const float* __restrict__ s1,
                 const float* __restrict__ s2, const float* __restrict__ s3,
                 const float* __restrict__ s4,
                 unsigned short* __restrict__ d0, unsigned short* __restrict__ d1,
                 unsigned short* __restrict__ d2, unsigned short* __restrict__ d3,
                 unsigned short* __restrict__ d4,
                 int n0, int n1, int n2, int n3, int n4) {
  const int start = blockIdx.x * 256 + threadIdx.x;
  const int stride = gridDim.x * 256;
  cvt_region(s0, d0, n0, start, stride);
  cvt_region(s1, d1, n1, start, stride);
  cvt_region(s2, d2, n2, start, stride);
  cvt_region(s3, d3, n3, start, stride);
  cvt_region(s4, d4, n4, start, stride);
}

// ---------------------------------------------------------------------------
// GEMM 1: QKV projection, 8-phase 256x256 template (T2+T3+T4+T5). Unchanged
// from round 8 (120 us, bank-conflict 0, best measured).
// ---------------------------------------------------------------------------
__global__ __launch_bounds__(512, 2)
void gemm_qkv_8ph(const unsigned short* __restrict__ hsb,
                  const unsigned short* __restrict__ Wqb,
                  const unsigned short* __restrict__ Wkb,
                  const unsigned short* __restrict__ Wvb,
                  unsigned short* __restrict__ Qb,
                  unsigned short* __restrict__ Kb,
                  unsigned short* __restrict__ Vb) {
  const int K = 4096;
  const int NT = 64;
  __shared__ __align__(16) unsigned short Ls[2][2][2][256][32]; // 128 KiB
  const int tid = threadIdx.x, lane = tid & 63, w = tid >> 6;
  const int wr = w >> 2, wc = w & 3;
  const int m0 = blockIdx.y * 256;
  const int n0g = blockIdx.x * 256;

  const unsigned short* Bsrc; unsigned short* outp; int ldo, oc;
  if (n0g < 4096)      { Bsrc = Wqb + (size_t)n0g * K;          outp = Qb; ldo = 4096; oc = n0g; }
  else if (n0g < 5120) { Bsrc = Wkb + (size_t)(n0g - 4096) * K; outp = Kb; ldo = 1024; oc = n0g - 4096; }
  else                 { Bsrc = Wvb + (size_t)(n0g - 5120) * K; outp = Vb; ldo = 1024; oc = n0g - 5120; }
  const unsigned short* Asrc = hsb + (size_t)m0 * K;

  auto stageU = [&](const unsigned short* src, int ab, int kh, int tt, int bb) {
#pragma unroll
    for (int j = 0; j < 2; ++j) {
      const int seg = j * 8 + w;
      const int row = seg * 16 + (lane >> 2);
      const int cs  = (lane & 3) ^ ((row >> 1) & 3);
      gl2lds16(src + (size_t)row * K + tt * 64 + kh * 32 + cs * 8,
               &Ls[bb][ab][kh][seg * 16][0]);
    }
  };
  auto ldA = [&](int bb, int kh, int fm) -> short8 {
    const int ra = wr * 128 + fm * 16 + (lane & 15);
    const int cs = (lane >> 4) ^ ((ra >> 1) & 3);
    return *(const short8*)&Ls[bb][0][kh][ra][cs * 8];
  };
  auto ldB = [&](int bb, int kh, int fn) -> short8 {
    const int rb = wc * 64 + fn * 16 + (lane & 15);
    const int cs = (lane >> 4) ^ ((rb >> 1) & 3);
    return *(const short8*)&Ls[bb][1][kh][rb][cs * 8];
  };

  f32x4 acc[8][4];
#pragma unroll
  for (int i = 0; i < 8; ++i)
#pragma unroll
    for (int j = 0; j < 4; ++j) acc[i][j] = (f32x4){0.f, 0.f, 0.f, 0.f};

  stageU(Asrc, 0, 0, 0, 0);
  stageU(Asrc, 0, 1, 0, 0);
  stageU(Bsrc, 1, 0, 0, 0);
  stageU(Bsrc, 1, 1, 0, 0);
  stageU(Bsrc, 1, 0, 1, 1);
  stageU(Asrc, 0, 0, 1, 1);
  stageU(Bsrc, 1, 1, 1, 1);
  asm volatile("s_waitcnt vmcnt(6)" ::: "memory");
  bar();
  sfence();

  short8 af[4], bfr[4];
  for (int t = 0; t < NT; ++t) {
    const int bb = t & 1, nb = bb ^ 1;
    // P1: (kh0, mq0); stage A(t+1)-kh1 -> nb
#pragma unroll
    for (int i = 0; i < 4; ++i) af[i] = ldA(bb, 0, i);
#pragma unroll
    for (int i = 0; i < 4; ++i) bfr[i] = ldB(bb, 0, i);
    if (t + 1 < NT) stageU(Asrc, 0, 1, t + 1, nb);
    bar();
    __builtin_amdgcn_s_setprio(1);
#pragma unroll
    for (int i = 0; i < 4; ++i)
#pragma unroll
      for (int j = 0; j < 4; ++j) acc[i][j] = mfma16(af[i], bfr[j], acc[i][j]);
    __builtin_amdgcn_s_setprio(0);
    sfence(); bar(); sfence();
    // P2: (kh0, mq1); stage B(t+2)-kh0 -> bb
#pragma unroll
    for (int i = 0; i < 4; ++i) af[i] = ldA(bb, 0, 4 + i);
    if (t + 2 < NT) stageU(Bsrc, 1, 0, t + 2, bb);
    bar();
    __builtin_amdgcn_s_setprio(1);
#pragma unroll
    for (int i = 0; i < 4; ++i)
#pragma unroll
      for (int j = 0; j < 4; ++j) acc[4 + i][j] = mfma16(af[i], bfr[j], acc[4 + i][j]);
    __builtin_amdgcn_s_setprio(0);
    sfence(); bar(); sfence();
    // P3: (kh1, mq0); stage A(t+2)-kh0 -> bb
#pragma unroll
    for (int i = 0; i < 4; ++i) af[i] = ldA(bb, 1, i);
#pragma unroll
    for (int i = 0; i < 4; ++i) bfr[i] = ldB(bb, 1, i);
    if (t + 2 < NT) stageU(Asrc, 0, 0, t + 2, bb);
    bar();
    __builtin_amdgcn_s_setprio(1);
#pragma unroll
    for (int i = 0; i < 4; ++i)
#pragma unroll
      for (int j = 0; j < 4; ++j) acc[i][j] = mfma16(af[i], bfr[j], acc[i][j]);
    __builtin_amdgcn_s_setprio(0);
    sfence(); bar(); sfence();
    // P4: (kh1, mq1); stage B(t+2)-kh1 -> bb; counted vmcnt
#pragma unroll
    for (int i = 0; i < 4; ++i) af[i] = ldA(bb, 1, 4 + i);
    if (t + 2 < NT) stageU(Bsrc, 1, 1, t + 2, bb);
    bar();
    __builtin_amdgcn_s_setprio(1);
#pragma unroll
    for (int i = 0; i < 4; ++i)
#pragma unroll
      for (int j = 0; j < 4; ++j) acc[4 + i][j] = mfma16(af[i], bfr[j], acc[4 + i][j]);
    __builtin_amdgcn_s_setprio(0);
    if (t < NT - 2) asm volatile("s_waitcnt vmcnt(6)" ::: "memory");
    else            asm volatile("s_waitcnt vmcnt(0)" ::: "memory");
    sfence(); bar(); sfence();
  }

#pragma unroll
  for (int fm = 0; fm < 8; ++fm) {
    const int rb0 = m0 + wr * 128 + fm * 16 + ((lane >> 4) << 2);
#pragma unroll
    for (int fn = 0; fn < 4; ++fn) {
      const int cb = oc + wc * 64 + fn * 16 + (lane & 15);
#pragma unroll
      for (int r = 0; r < 4; ++r)
        outp[(size_t)(rb0 + r) * ldo + cb] = f2bf(acc[fm][fn][r]);
    }
  }
}

// ---------------------------------------------------------------------------
// Postproc (one launch): blocks 0..511 = V transpose; rest = RoPE on Q,K.
// ---------------------------------------------------------------------------
__global__ __launch_bounds__(256)
void postproc_kernel(const unsigned short* __restrict__ Vb,
                     unsigned short* __restrict__ VtG,
                     unsigned short* __restrict__ Qb,
                     unsigned short* __restrict__ Kb,
                     const int* __restrict__ posp) {
  __shared__ unsigned short tile[64][68];
  const int b = blockIdx.x, tid = threadIdx.x;
  if (b < 512) {
    // V transpose: Vb [2048][1024] -> VtG [1024][2048]
    const int t0 = (b & 31) * 64;
    const int c0 = (b >> 5) * 64;
    const int r = tid >> 4;
    const int c4 = (tid & 15) << 2;
#pragma unroll
    for (int i = 0; i < 4; ++i) {
      ushort4 v = *(const ushort4*)(Vb + (size_t)(t0 + r + i * 16) * 1024 + c0 + c4);
      *(ushort4*)&tile[r + i * 16][c4] = v;
    }
    __syncthreads();
#pragma unroll
    for (int i = 0; i < 4; ++i) {
      int d = r + i * 16;
      ushort4 o;
      o.x = tile[c4 + 0][d]; o.y = tile[c4 + 1][d];
      o.z = tile[c4 + 2][d]; o.w = tile[c4 + 3][d];
      *(ushort4*)(VtG + (size_t)(c0 + d) * 2048 + t0 + c4) = o;
    }
    return;
  }
  // RoPE
  const int QP = 2048 * 32 * 64;
  const int KP = 2048 * 8 * 64;
  int idx = (b - 512) * 256 + tid;
  if (idx >= QP + KP) return;
  unsigned short* base; int t, hh, d, ld;
  if (idx < QP) {
    base = Qb; ld = 4096;
    t = idx >> 11; int rem = idx & 2047; hh = rem >> 6; d = rem & 63;
  } else {
    int j = idx - QP; base = Kb; ld = 1024;
    t = j >> 9; int rem = j & 511; hh = rem >> 6; d = rem & 63;
  }
  float freq = exp2f(-(float)d * 0.29580575880077f);  // 500000^(-2d/128)
  float ang = (float)(t + posp[0]) * freq;
  float s, c;
  __sincosf(ang, &s, &c);
  size_t i1 = (size_t)t * ld + hh * 128 + d;
  float x1 = bf2f(base[i1]), x2 = bf2f(base[i1 + 64]);
  base[i1]      = f2bf(x1 * c - x2 * s);
  base[i1 + 64] = f2bf(x1 * s + x2 * c);
}

// ---------------------------------------------------------------------------
// Causal GQA flash attention. 512 thr = 8 waves x 16 q-rows, KVBLK=128.
// K and V^T staged via global_load_lds with pre-swizzled source (96 KB LDS).
// Complementary qt pairing balances per-CU work.
// ---------------------------------------------------------------------------
__global__ __launch_bounds__(512)
void attn_kernel(const unsigned short* __restrict__ Qb,
                 const unsigned short* __restrict__ Kb,
                 const unsigned short* __restrict__ VtG,
                 unsigned short* __restrict__ Ob) {
  __shared__ __align__(16) unsigned short Ks[128][128];   // [s][d], swz ^((s&7)<<4)
  __shared__ __align__(16) unsigned short Vt[128][128];   // [d][s], swz ^((d&7)<<4)
  __shared__ __align__(16) unsigned short Ps[8][16][128]; // per-wave P, swz ^(((row>>2)&3)<<5)
  const int tid = threadIdx.x, lane = tid & 63, w = tid >> 6;
  const int h = blockIdx.y;
  const int qt = (blockIdx.y >> 4) ? (15 - blockIdx.x) : blockIdx.x;
  const int kh = h >> 2;
  const int q0 = qt * 128;
  const float SCALE = 0.08838834764831845f;

  short8 aq[4];
  {
    const int qrow = q0 + w * 16 + (lane & 15);
#pragma unroll
    for (int ks = 0; ks < 4; ++ks)
      aq[ks] = *(const short8*)(Qb + (size_t)qrow * 4096 + h * 128 + ks * 32 +
                                ((lane >> 4) << 3));
  }

  f32x4 o_acc[8];
#pragma unroll
  for (int n8 = 0; n8 < 8; ++n8) o_acc[n8] = (f32x4){0.f, 0.f, 0.f, 0.f};
  float mst[4], lst[4];
#pragma unroll
  for (int r = 0; r < 4; ++r) { mst[r] = -1e30f; lst[r] = 0.f; }

  const int ntiles = qt + 1;
  for (int st = 0; st < ntiles; ++st) {
    const int s0 = st * 128;
    // stage K: wave w covers rows w*16..w*16+15 (4 units of 4 rows)
#pragma unroll
    for (int j = 0; j < 4; ++j) {
      int sr = w * 16 + j * 4 + (lane >> 4);
      int sc = (((lane & 15) << 4) ^ ((sr & 7) << 4)) >> 1;
      gl2lds16(Kb + (size_t)(s0 + sr) * 1024 + kh * 128 + sc, &Ks[w * 16 + j * 4][0]);
    }
    // stage V^T: wave w covers d-rows w*16..w*16+15
#pragma unroll
    for (int j = 0; j < 4; ++j) {
      int dr = w * 16 + j * 4 + (lane >> 4);
      int sc = (((lane & 15) << 4) ^ ((dr & 7) << 4)) >> 1;
      gl2lds16(VtG + (size_t)(kh * 128 + dr) * 2048 + s0 + sc, &Vt[w * 16 + j * 4][0]);
    }
    __syncthreads();

    // S = Q K^T (16 q-rows x 128 keys per wave)
    f32x4 sacc[8];
#pragma unroll
    for (int ni = 0; ni < 8; ++ni) sacc[ni] = (f32x4){0.f, 0.f, 0.f, 0.f};
#pragma unroll
    for (int ks = 0; ks < 4; ++ks) {
      const int co = ks * 64 + ((lane >> 4) << 4);
      short8 bk[8];
#pragma unroll
      for (int ni = 0; ni < 8; ++ni) {
        int kr = ni * 16 + (lane & 15);
        bk[ni] = *(const short8*)((const char*)(&Ks[kr][0]) + (co ^ ((kr & 7) << 4)));
      }
#pragma unroll
      for (int ni = 0; ni < 8; ++ni)
        sacc[ni] = mfma16(aq[ks], bk[ni], sacc[ni]);
    }

    // online softmax; write P to this wave's LDS region
    char* pb = (char*)(&Ps[w][0][0]);
#pragma unroll
    for (int r = 0; r < 4; ++r) {
      const int qrow = q0 + w * 16 + ((lane >> 4) << 2) + r;
      float v8[8]; float vmax = -1e30f;
#pragma unroll
      for (int ni = 0; ni < 8; ++ni) {
        int scol = s0 + ni * 16 + (lane & 15);
        float x = sacc[ni][r] * SCALE;
        if (scol > qrow) x = -1e30f;
        v8[ni] = x; vmax = fmaxf(vmax, x);
      }
      vmax = fmaxf(vmax, __shfl_xor(vmax, 1));
      vmax = fmaxf(vmax, __shfl_xor(vmax, 2));
      vmax = fmaxf(vmax, __shfl_xor(vmax, 4));
      vmax = fmaxf(vmax, __shfl_xor(vmax, 8));
      float mo = mst[r];
      float mn = fmaxf(mo, vmax);
      float al = __expf(mo - mn);
      float rs = 0.f;
      const int prow = ((lane >> 4) << 2) + r;
      const int pswz = ((prow >> 2) & 3) << 5;
#pragma unroll
      for (int ni = 0; ni < 8; ++ni) {
        float p = __expf(v8[ni] - mn);
        rs += p;
        int cbyte = (ni * 16 + (lane & 15)) * 2;
        *(unsigned short*)(pb + prow * 256 + (cbyte ^ pswz)) = f2bf(p);
      }
      rs += __shfl_xor(rs, 1);
      rs += __shfl_xor(rs, 2);
      rs += __shfl_xor(rs, 4);
      rs += __shfl_xor(rs, 8);
      lst[r] = lst[r] * al + rs;
      mst[r] = mn;
#pragma unroll
      for (int n8 = 0; n8 < 8; ++n8) o_acc[n8][r] *= al;
    }

    // O += P V  (P 16x128 from own-wave LDS; V^T tile)
#pragma unroll
    for (int ks2 = 0; ks2 < 4; ++ks2) {
      const int co = ks2 * 64 + ((lane >> 4) << 4);
      const int pr = lane & 15;
      short8 pa = *(const short8*)(pb + pr * 256 + (co ^ (((pr >> 2) & 3) << 5)));
#pragma unroll
      for (int n8 = 0; n8 < 8; ++n8) {
        int vr = n8 * 16 + (lane & 15);
        short8 bv = *(const short8*)((const char*)(&Vt[vr][0]) + (co ^ ((vr & 7) << 4)));
        o_acc[n8] = mfma16(pa, bv, o_acc[n8]);
      }
    }
    __syncthreads();
  }

#pragma unroll
  for (int r = 0; r < 4; ++r) {
    float inv = 1.0f / lst[r];
    int row = q0 + w * 16 + ((lane >> 4) << 2) + r;
#pragma unroll
    for (int n8 = 0; n8 < 8; ++n8)
      Ob[(size_t)row * 4096 + h * 128 + n8 * 16 + (lane & 15)] =
          f2bf(o_acc[n8][r] * inv);
  }
}

// ---------------------------------------------------------------------------
// GEMM 2 (m97 structure): O projection, fp32 out. Unchanged.
// ---------------------------------------------------------------------------
__global__ __launch_bounds__(256, 2)
void gemm_out_bf16(const unsigned short* __restrict__ Ab,
                   const unsigned short* __restrict__ Wob,
                   float* __restrict__ Cout) {
  const int K = 4096;
  __shared__ __align__(16) unsigned short As[128][64];
  __shared__ __align__(16) unsigned short Bs[128][64];
  const int tid = threadIdx.x, lane = tid & 63, wid = tid >> 6;
  const int m0 = blockIdx.y * 128;
  const int n0 = blockIdx.x * 128;
  const unsigned short* Asrc = Ab + (size_t)m0 * K;
  const unsigned short* Bsrc = Wob + (size_t)n0 * K;

  f32x4 acc[4][4];
#pragma unroll
  for (int i = 0; i < 4; ++i)
#pragma unroll
    for (int j = 0; j < 4; ++j) acc[i][j] = (f32x4){0.f, 0.f, 0.f, 0.f};

  const int wm = (wid >> 1) * 64, wn = (wid & 1) * 64;
  const int srow = wid * 32 + (lane >> 3);
  const int scol = (lane & 7) * 8;

  for (int k0 = 0; k0 < K; k0 += 64) {
#pragma unroll
    for (int i = 0; i < 4; ++i) {
      gl2lds16(Asrc + (size_t)(srow + i * 8) * K + k0 + scol, &As[wid * 32 + i * 8][0]);
      gl2lds16(Bsrc + (size_t)(srow + i * 8) * K + k0 + scol, &Bs[wid * 32 + i * 8][0]);
    }
    __syncthreads();
#pragma unroll
    for (int ks = 0; ks < 2; ++ks) {
      short8 af[4], bfr[4];
      const int co = ks * 64 + ((lane >> 4) << 4);
#pragma unroll
      for (int i = 0; i < 4; ++i) {
        af[i]  = *(const short8*)((const char*)(&As[wm + i * 16 + (lane & 15)][0]) + co);
        bfr[i] = *(const short8*)((const char*)(&Bs[wn + i * 16 + (lane & 15)][0]) + co);
      }
#pragma unroll
      for (int i = 0; i < 4; ++i)
#pragma unroll
        for (int j = 0; j < 4; ++j)
          acc[i][j] = mfma16(af[i], bfr[j], acc[i][j]);
    }
    __syncthreads();
  }

#pragma unroll
  for (int i = 0; i < 4; ++i) {
    int rb = m0 + wm + i * 16 + ((lane >> 4) << 2);
#pragma unroll
    for (int j = 0; j < 4; ++j) {
      int cb = n0 + wn + j * 16 + (lane & 15);
#pragma unroll
      for (int r = 0; r < 4; ++r)
        Cout[(size_t)(rb + r) * 4096 + cb] = acc[i][j][r];
    }
  }
}

extern "C" void kernel_launch(void* const* d_in, const int* in_sizes, int n_in,
                              void* d_out, int out_size, void* d_ws, size_t ws_size,
                              hipStream_t stream) {
  const float* hs = (const float*)d_in[0];
  const float* Wq = (const float*)d_in[1];
  const float* Wk = (const float*)d_in[2];
  const float* Wv = (const float*)d_in[3];
  const float* Wo = (const float*)d_in[4];
  const int* pos = (const int*)d_in[7];

  unsigned short* hsb = (unsigned short*)d_ws;              // 8M
  unsigned short* Wqb = hsb + (size_t)8  * 1024 * 1024;     // 16M
  unsigned short* Wkb = Wqb + (size_t)16 * 1024 * 1024;     // 4M
  unsigned short* Wvb = Wkb + (size_t)4  * 1024 * 1024;     // 4M
  unsigned short* Wob = Wvb + (size_t)4  * 1024 * 1024;     // 16M
  unsigned short* Qb  = Wob + (size_t)16 * 1024 * 1024;     // 8M
  unsigned short* Kb  = Qb  + (size_t)8  * 1024 * 1024;     // 2M
  unsigned short* Vb  = Kb  + (size_t)2  * 1024 * 1024;     // 2M
  unsigned short* Ob  = Vb  + (size_t)2  * 1024 * 1024;     // 8M
  unsigned short* VtG = hsb;  // aliases hsb (dead after QKV GEMM; cvt rewrites)
  float* out = (float*)d_out;

  cvt5_kernel<<<dim3(2048), 256, 0, stream>>>(
      hs, Wq, Wk, Wv, Wo, hsb, Wqb, Wkb, Wvb, Wob,
      2 * 1024 * 1024, 4 * 1024 * 1024, 1 * 1024 * 1024, 1 * 1024 * 1024,
      4 * 1024 * 1024);

  gemm_qkv_8ph<<<dim3(24, 8), 512, 0, stream>>>(hsb, Wqb, Wkb, Wvb, Qb, Kb, Vb);

  const int npairs = 2048 * 32 * 64 + 2048 * 8 * 64;
  const int rope_blocks = (npairs + 255) / 256;
  postproc_kernel<<<dim3(512 + rope_blocks), 256, 0, stream>>>(Vb, VtG, Qb, Kb, pos);

  attn_kernel<<<dim3(16, 32), 512, 0, stream>>>(Qb, Kb, VtG, Ob);
  gemm_out_bf16<<<dim3(32, 16), 256, 0, stream>>>(Ob, Wob, out);
}

// Round 11
// 359.699 us; speedup vs baseline: 2.2187x; 1.0200x over previous
//
#include <hip/hip_runtime.h>

// Fused GQA prefill: cvt5(fp32->bf16) -> QKV proj (8-phase 256^2, XCD-mapped)
// -> postproc(V-transpose + RoPE) -> causal flash attn (8-wave, KVBLK=64,
// double-buffered counted-vmcnt, XCD kh-locality) -> O proj (m97, XCD-mapped).
// B=1, T=2048, HID=4096, H=32, HKV=8, DH=128, pos=0.

#define DEVI __device__ __forceinline__

typedef __attribute__((ext_vector_type(8))) short short8;
typedef __attribute__((ext_vector_type(4))) float f32x4;

DEVI unsigned short f2bf(float f) {
  union { float f; unsigned u; } x; x.f = f;
  unsigned r = x.u + 0x7FFFu + ((x.u >> 16) & 1u);
  return (unsigned short)(r >> 16);
}
DEVI float bf2f(unsigned short h) {
  union { unsigned u; float f; } x; x.u = ((unsigned)h) << 16;
  return x.f;
}
DEVI f32x4 mfma16(short8 a, short8 b, f32x4 c) {
  return __builtin_amdgcn_mfma_f32_16x16x32_bf16(a, b, c, 0, 0, 0);
}
DEVI void gl2lds16(const unsigned short* g, unsigned short* l) {
  __builtin_amdgcn_global_load_lds(
      (const __attribute__((address_space(1))) unsigned int*)g,
      (__attribute__((address_space(3))) unsigned int*)l, 16, 0, 0);
}
DEVI void bar() { __builtin_amdgcn_s_barrier(); }
DEVI void sfence() { __builtin_amdgcn_sched_barrier(0); }

// ---------------------------------------------------------------------------
// One-launch fp32 -> bf16 conversion of all 5 tensors (grid-stride each).
// ---------------------------------------------------------------------------
DEVI void cvt_region(const float* __restrict__ src,
                     unsigned short* __restrict__ dst, int n4, int start,
                     int stride) {
  for (int i = start; i < n4; i += stride) {
    float4 v = ((const float4*)src)[i];
    ushort4 h;
    h.x = f2bf(v.x); h.y = f2bf(v.y); h.z = f2bf(v.z); h.w = f2bf(v.w);
    ((ushort4*)dst)[i] = h;
  }
}
__global__ __launch_bounds__(256)
void cvt5_kernel(const float* __restrict__ s0, const float* __restrict__ s1,
                 const float* __restrict__ s2, const float* __restrict__ s3,
                 const float* __restrict__ s4,
                 unsigned short* __restrict__ d0, unsigned short* __restrict__ d1,
                 unsigned short* __restrict__ d2, unsigned short* __restrict__ d3,
                 unsigned short* __restrict__ d4,
                 int n0, int n1, int n2, int n3, int n4) {
  const int start = blockIdx.x * 256 + threadIdx.x;
  const int stride = gridDim.x * 256;
  cvt_region(s0, d0, n0, start, stride);
  cvt_region(s1, d1, n1, start, stride);
  cvt_region(s2, d2, n2, start, stride);
  cvt_region(s3, d3, n3, start, stride);
  cvt_region(s4, d4, n4, start, stride);
}

// ---------------------------------------------------------------------------
// GEMM 1: QKV projection, 8-phase 256x256 template. 1D grid, by = bid&7 so
// each XCD keeps one 2MB A-panel L2-resident.
// ---------------------------------------------------------------------------
__global__ __launch_bounds__(512, 2)
void gemm_qkv_8ph(const unsigned short* __restrict__ hsb,
                  const unsigned short* __restrict__ Wqb,
                  const unsigned short* __restrict__ Wkb,
                  const unsigned short* __restrict__ Wvb,
                  unsigned short* __restrict__ Qb,
                  unsigned short* __restrict__ Kb,
                  unsigned short* __restrict__ Vb) {
  const int K = 4096;
  const int NT = 64;
  __shared__ __align__(16) unsigned short Ls[2][2][2][256][32]; // 128 KiB
  const int tid = threadIdx.x, lane = tid & 63, w = tid >> 6;
  const int wr = w >> 2, wc = w & 3;
  const int bid = blockIdx.x;            // 0..191
  const int m0 = (bid & 7) * 256;        // XCD-resident A panel
  const int n0g = (bid >> 3) * 256;

  const unsigned short* Bsrc; unsigned short* outp; int ldo, oc;
  if (n0g < 4096)      { Bsrc = Wqb + (size_t)n0g * K;          outp = Qb; ldo = 4096; oc = n0g; }
  else if (n0g < 5120) { Bsrc = Wkb + (size_t)(n0g - 4096) * K; outp = Kb; ldo = 1024; oc = n0g - 4096; }
  else                 { Bsrc = Wvb + (size_t)(n0g - 5120) * K; outp = Vb; ldo = 1024; oc = n0g - 5120; }
  const unsigned short* Asrc = hsb + (size_t)m0 * K;

  auto stageU = [&](const unsigned short* src, int ab, int kh, int tt, int bb) {
#pragma unroll
    for (int j = 0; j < 2; ++j) {
      const int seg = j * 8 + w;
      const int row = seg * 16 + (lane >> 2);
      const int cs  = (lane & 3) ^ ((row >> 1) & 3);
      gl2lds16(src + (size_t)row * K + tt * 64 + kh * 32 + cs * 8,
               &Ls[bb][ab][kh][seg * 16][0]);
    }
  };
  auto ldA = [&](int bb, int kh, int fm) -> short8 {
    const int ra = wr * 128 + fm * 16 + (lane & 15);
    const int cs = (lane >> 4) ^ ((ra >> 1) & 3);
    return *(const short8*)&Ls[bb][0][kh][ra][cs * 8];
  };
  auto ldB = [&](int bb, int kh, int fn) -> short8 {
    const int rb = wc * 64 + fn * 16 + (lane & 15);
    const int cs = (lane >> 4) ^ ((rb >> 1) & 3);
    return *(const short8*)&Ls[bb][1][kh][rb][cs * 8];
  };

  f32x4 acc[8][4];
#pragma unroll
  for (int i = 0; i < 8; ++i)
#pragma unroll
    for (int j = 0; j < 4; ++j) acc[i][j] = (f32x4){0.f, 0.f, 0.f, 0.f};

  stageU(Asrc, 0, 0, 0, 0);
  stageU(Asrc, 0, 1, 0, 0);
  stageU(Bsrc, 1, 0, 0, 0);
  stageU(Bsrc, 1, 1, 0, 0);
  stageU(Bsrc, 1, 0, 1, 1);
  stageU(Asrc, 0, 0, 1, 1);
  stageU(Bsrc, 1, 1, 1, 1);
  asm volatile("s_waitcnt vmcnt(6)" ::: "memory");
  bar();
  sfence();

  short8 af[4], bfr[4];
  for (int t = 0; t < NT; ++t) {
    const int bb = t & 1, nb = bb ^ 1;
    // P1: (kh0, mq0); stage A(t+1)-kh1 -> nb
#pragma unroll
    for (int i = 0; i < 4; ++i) af[i] = ldA(bb, 0, i);
#pragma unroll
    for (int i = 0; i < 4; ++i) bfr[i] = ldB(bb, 0, i);
    if (t + 1 < NT) stageU(Asrc, 0, 1, t + 1, nb);
    bar();
    __builtin_amdgcn_s_setprio(1);
#pragma unroll
    for (int i = 0; i < 4; ++i)
#pragma unroll
      for (int j = 0; j < 4; ++j) acc[i][j] = mfma16(af[i], bfr[j], acc[i][j]);
    __builtin_amdgcn_s_setprio(0);
    sfence(); bar(); sfence();
    // P2: (kh0, mq1); stage B(t+2)-kh0 -> bb
#pragma unroll
    for (int i = 0; i < 4; ++i) af[i] = ldA(bb, 0, 4 + i);
    if (t + 2 < NT) stageU(Bsrc, 1, 0, t + 2, bb);
    bar();
    __builtin_amdgcn_s_setprio(1);
#pragma unroll
    for (int i = 0; i < 4; ++i)
#pragma unroll
      for (int j = 0; j < 4; ++j) acc[4 + i][j] = mfma16(af[i], bfr[j], acc[4 + i][j]);
    __builtin_amdgcn_s_setprio(0);
    sfence(); bar(); sfence();
    // P3: (kh1, mq0); stage A(t+2)-kh0 -> bb
#pragma unroll
    for (int i = 0; i < 4; ++i) af[i] = ldA(bb, 1, i);
#pragma unroll
    for (int i = 0; i < 4; ++i) bfr[i] = ldB(bb, 1, i);
    if (t + 2 < NT) stageU(Asrc, 0, 0, t + 2, bb);
    bar();
    __builtin_amdgcn_s_setprio(1);
#pragma unroll
    for (int i = 0; i < 4; ++i)
#pragma unroll
      for (int j = 0; j < 4; ++j) acc[i][j] = mfma16(af[i], bfr[j], acc[i][j]);
    __builtin_amdgcn_s_setprio(0);
    sfence(); bar(); sfence();
    // P4: (kh1, mq1); stage B(t+2)-kh1 -> bb; counted vmcnt
#pragma unroll
    for (int i = 0; i < 4; ++i) af[i] = ldA(bb, 1, 4 + i);
    if (t + 2 < NT) stageU(Bsrc, 1, 1, t + 2, bb);
    bar();
    __builtin_amdgcn_s_setprio(1);
#pragma unroll
    for (int i = 0; i < 4; ++i)
#pragma unroll
      for (int j = 0; j < 4; ++j) acc[4 + i][j] = mfma16(af[i], bfr[j], acc[4 + i][j]);
    __builtin_amdgcn_s_setprio(0);
    if (t < NT - 2) asm volatile("s_waitcnt vmcnt(6)" ::: "memory");
    else            asm volatile("s_waitcnt vmcnt(0)" ::: "memory");
    sfence(); bar(); sfence();
  }

#pragma unroll
  for (int fm = 0; fm < 8; ++fm) {
    const int rb0 = m0 + wr * 128 + fm * 16 + ((lane >> 4) << 2);
#pragma unroll
    for (int fn = 0; fn < 4; ++fn) {
      const int cb = oc + wc * 64 + fn * 16 + (lane & 15);
#pragma unroll
      for (int r = 0; r < 4; ++r)
        outp[(size_t)(rb0 + r) * ldo + cb] = f2bf(acc[fm][fn][r]);
    }
  }
}

// ---------------------------------------------------------------------------
// Postproc (one launch): blocks 0..511 = V transpose; rest = RoPE on Q,K.
// ---------------------------------------------------------------------------
__global__ __launch_bounds__(256)
void postproc_kernel(const unsigned short* __restrict__ Vb,
                     unsigned short* __restrict__ VtG,
                     unsigned short* __restrict__ Qb,
                     unsigned short* __restrict__ Kb,
                     const int* __restrict__ posp) {
  __shared__ unsigned short tile[64][68];
  const int b = blockIdx.x, tid = threadIdx.x;
  if (b < 512) {
    const int t0 = (b & 31) * 64;
    const int c0 = (b >> 5) * 64;
    const int r = tid >> 4;
    const int c4 = (tid & 15) << 2;
#pragma unroll
    for (int i = 0; i < 4; ++i) {
      ushort4 v = *(const ushort4*)(Vb + (size_t)(t0 + r + i * 16) * 1024 + c0 + c4);
      *(ushort4*)&tile[r + i * 16][c4] = v;
    }
    __syncthreads();
#pragma unroll
    for (int i = 0; i < 4; ++i) {
      int d = r + i * 16;
      ushort4 o;
      o.x = tile[c4 + 0][d]; o.y = tile[c4 + 1][d];
      o.z = tile[c4 + 2][d]; o.w = tile[c4 + 3][d];
      *(ushort4*)(VtG + (size_t)(c0 + d) * 2048 + t0 + c4) = o;
    }
    return;
  }
  const int QP = 2048 * 32 * 64;
  const int KP = 2048 * 8 * 64;
  int idx = (b - 512) * 256 + tid;
  if (idx >= QP + KP) return;
  unsigned short* base; int t, hh, d, ld;
  if (idx < QP) {
    base = Qb; ld = 4096;
    t = idx >> 11; int rem = idx & 2047; hh = rem >> 6; d = rem & 63;
  } else {
    int j = idx - QP; base = Kb; ld = 1024;
    t = j >> 9; int rem = j & 511; hh = rem >> 6; d = rem & 63;
  }
  float freq = exp2f(-(float)d * 0.29580575880077f);  // 500000^(-2d/128)
  float ang = (float)(t + posp[0]) * freq;
  float s, c;
  __sincosf(ang, &s, &c);
  size_t i1 = (size_t)t * ld + hh * 128 + d;
  float x1 = bf2f(base[i1]), x2 = bf2f(base[i1 + 64]);
  base[i1]      = f2bf(x1 * c - x2 * s);
  base[i1 + 64] = f2bf(x1 * s + x2 * c);
}

// ---------------------------------------------------------------------------
// Causal GQA flash attention. 512 thr = 8 waves x 16 q-rows, KVBLK=64,
// double-buffered K/V with counted vmcnt (stage st+1 issued before compute,
// raw s_barrier, never drain to 0 mid-loop). 1D grid: kh = b&7 keeps each
// XCD's K/V slice (1MB) + Q slice (2MB) L2-resident; (b, b+256) pair gives
// balanced qt work per CU.
// ---------------------------------------------------------------------------
__global__ __launch_bounds__(512)
void attn_kernel(const unsigned short* __restrict__ Qb,
                 const unsigned short* __restrict__ Kb,
                 const unsigned short* __restrict__ VtG,
                 unsigned short* __restrict__ Ob) {
  __shared__ __align__(16) unsigned short Ks[2][64][128];  // swz ^((s&7)<<4)
  __shared__ __align__(16) unsigned short Vt[2][128][64];  // swz ^((d&7)<<4)
  __shared__ __align__(16) unsigned short Ps[8][16][64];   // swz ^(((row>>2)&3)<<5)
  const int tid = threadIdx.x, lane = tid & 63, w = tid >> 6;
  const int b = blockIdx.x;
  const int kh = b & 7;
  const int h  = kh * 4 + ((b >> 3) & 3);
  const int qi = b >> 5;                       // 0..15
  const int qt = (qi < 8) ? qi : 23 - qi;      // balanced pairing (b, b+256)
  const int q0 = qt * 128;
  const float SCALE = 0.08838834764831845f;

  short8 aq[4];
  {
    const int qrow = q0 + w * 16 + (lane & 15);
#pragma unroll
    for (int ks = 0; ks < 4; ++ks)
      aq[ks] = *(const short8*)(Qb + (size_t)qrow * 4096 + h * 128 + ks * 32 +
                                ((lane >> 4) << 3));
  }

  f32x4 o_acc[8];
#pragma unroll
  for (int n8 = 0; n8 < 8; ++n8) o_acc[n8] = (f32x4){0.f, 0.f, 0.f, 0.f};
  float mst[4], lst[4];
#pragma unroll
  for (int r = 0; r < 4; ++r) { mst[r] = -1e30f; lst[r] = 0.f; }

  // stage one KV tile (4 gl2lds per wave) into buffer bb
  auto stage = [&](int st, int bb) {
    const int s0 = st * 64;
#pragma unroll
    for (int j = 0; j < 2; ++j) {
      int sr = w * 8 + j * 4 + (lane >> 4);
      int sc = (((lane & 15) << 4) ^ ((sr & 7) << 4)) >> 1;
      gl2lds16(Kb + (size_t)(s0 + sr) * 1024 + kh * 128 + sc,
               &Ks[bb][w * 8 + j * 4][0]);
    }
#pragma unroll
    for (int j = 0; j < 2; ++j) {
      int dr = w * 16 + j * 8 + (lane >> 3);
      int sc = (((lane & 7) << 4) ^ ((dr & 7) << 4)) >> 1;
      gl2lds16(VtG + (size_t)(kh * 128 + dr) * 2048 + s0 + sc,
               &Vt[bb][w * 16 + j * 8][0]);
    }
  };

  const int ntiles = 2 * (qt + 1);
  stage(0, 0);
  for (int st = 0; st < ntiles; ++st) {
    const int cb = st & 1;
    const int s0 = st * 64;
    if (st + 1 < ntiles) {
      stage(st + 1, cb ^ 1);
      asm volatile("s_waitcnt vmcnt(4)" ::: "memory");  // tile st landed
    } else {
      asm volatile("s_waitcnt vmcnt(0)" ::: "memory");
    }
    bar(); sfence();

    // S = Q K^T (16 q-rows x 64 keys per wave)
    f32x4 sacc[4];
#pragma unroll
    for (int ni = 0; ni < 4; ++ni) sacc[ni] = (f32x4){0.f, 0.f, 0.f, 0.f};
#pragma unroll
    for (int ks = 0; ks < 4; ++ks) {
      const int co = ks * 64 + ((lane >> 4) << 4);
      short8 bk[4];
#pragma unroll
      for (int ni = 0; ni < 4; ++ni) {
        int kr = ni * 16 + (lane & 15);
        bk[ni] = *(const short8*)((const char*)(&Ks[cb][kr][0]) + (co ^ ((kr & 7) << 4)));
      }
#pragma unroll
      for (int ni = 0; ni < 4; ++ni)
        sacc[ni] = mfma16(aq[ks], bk[ni], sacc[ni]);
    }

    // online softmax; write P to this wave's LDS region
    char* pb = (char*)(&Ps[w][0][0]);
#pragma unroll
    for (int r = 0; r < 4; ++r) {
      const int qrow = q0 + w * 16 + ((lane >> 4) << 2) + r;
      float v4[4]; float vmax = -1e30f;
#pragma unroll
      for (int ni = 0; ni < 4; ++ni) {
        int scol = s0 + ni * 16 + (lane & 15);
        float x = sacc[ni][r] * SCALE;
        if (scol > qrow) x = -1e30f;
        v4[ni] = x; vmax = fmaxf(vmax, x);
      }
      vmax = fmaxf(vmax, __shfl_xor(vmax, 1));
      vmax = fmaxf(vmax, __shfl_xor(vmax, 2));
      vmax = fmaxf(vmax, __shfl_xor(vmax, 4));
      vmax = fmaxf(vmax, __shfl_xor(vmax, 8));
      float mo = mst[r];
      float mn = fmaxf(mo, vmax);
      float al = __expf(mo - mn);
      float rs = 0.f;
      const int prow = ((lane >> 4) << 2) + r;
      const int pswz = ((prow >> 2) & 3) << 5;
#pragma unroll
      for (int ni = 0; ni < 4; ++ni) {
        float p = __expf(v4[ni] - mn);
        rs += p;
        int cbyte = (ni * 16 + (lane & 15)) * 2;
        *(unsigned short*)(pb + prow * 128 + (cbyte ^ pswz)) = f2bf(p);
      }
      rs += __shfl_xor(rs, 1);
      rs += __shfl_xor(rs, 2);
      rs += __shfl_xor(rs, 4);
      rs += __shfl_xor(rs, 8);
      lst[r] = lst[r] * al + rs;
      mst[r] = mn;
#pragma unroll
      for (int n8 = 0; n8 < 8; ++n8) o_acc[n8][r] *= al;
    }

    // O += P V
#pragma unroll
    for (int ks2 = 0; ks2 < 2; ++ks2) {
      const int co = ks2 * 64 + ((lane >> 4) << 4);
      const int pr = lane & 15;
      short8 pa = *(const short8*)(pb + pr * 128 + (co ^ (((pr >> 2) & 3) << 5)));
#pragma unroll
      for (int n8 = 0; n8 < 8; ++n8) {
        int vr = n8 * 16 + (lane & 15);
        short8 bv = *(const short8*)((const char*)(&Vt[cb][vr][0]) + (co ^ ((vr & 7) << 4)));
        o_acc[n8] = mfma16(pa, bv, o_acc[n8]);
      }
    }
    sfence(); bar(); sfence();   // all waves done reading buf[cb]
  }

#pragma unroll
  for (int r = 0; r < 4; ++r) {
    float inv = 1.0f / lst[r];
    int row = q0 + w * 16 + ((lane >> 4) << 2) + r;
#pragma unroll
    for (int n8 = 0; n8 < 8; ++n8)
      Ob[(size_t)row * 4096 + h * 128 + n8 * 16 + (lane & 15)] =
          f2bf(o_acc[n8][r] * inv);
  }
}

// ---------------------------------------------------------------------------
// GEMM 2 (m97 structure): O projection, fp32 out. 1D grid with XCD map:
// XCD x owns m-panels {x, x+8} (2MB A L2-resident), streams Wo.
// ---------------------------------------------------------------------------
__global__ __launch_bounds__(256, 2)
void gemm_out_bf16(const unsigned short* __restrict__ Ab,
                   const unsigned short* __restrict__ Wob,
                   float* __restrict__ Cout) {
  const int K = 4096;
  __shared__ __align__(16) unsigned short As[128][64];
  __shared__ __align__(16) unsigned short Bs[128][64];
  const int tid = threadIdx.x, lane = tid & 63, wid = tid >> 6;
  const int bid = blockIdx.x;                       // 0..511
  const int m0 = (((bid & 7) + 8 * (bid >> 8))) * 128;
  const int n0 = ((bid >> 3) & 31) * 128;
  const unsigned short* Asrc = Ab + (size_t)m0 * K;
  const unsigned short* Bsrc = Wob + (size_t)n0 * K;

  f32x4 acc[4][4];
#pragma unroll
  for (int i = 0; i < 4; ++i)
#pragma unroll
    for (int j = 0; j < 4; ++j) acc[i][j] = (f32x4){0.f, 0.f, 0.f, 0.f};

  const int wm = (wid >> 1) * 64, wn = (wid & 1) * 64;
  const int srow = wid * 32 + (lane >> 3);
  const int scol = (lane & 7) * 8;

  for (int k0 = 0; k0 < K; k0 += 64) {
#pragma unroll
    for (int i = 0; i < 4; ++i) {
      gl2lds16(Asrc + (size_t)(srow + i * 8) * K + k0 + scol, &As[wid * 32 + i * 8][0]);
      gl2lds16(Bsrc + (size_t)(srow + i * 8) * K + k0 + scol, &Bs[wid * 32 + i * 8][0]);
    }
    __syncthreads();
#pragma unroll
    for (int ks = 0; ks < 2; ++ks) {
      short8 af[4], bfr[4];
      const int co = ks * 64 + ((lane >> 4) << 4);
#pragma unroll
      for (int i = 0; i < 4; ++i) {
        af[i]  = *(const short8*)((const char*)(&As[wm + i * 16 + (lane & 15)][0]) + co);
        bfr[i] = *(const short8*)((const char*)(&Bs[wn + i * 16 + (lane & 15)][0]) + co);
      }
#pragma unroll
      for (int i = 0; i < 4; ++i)
#pragma unroll
        for (int j = 0; j < 4; ++j)
          acc[i][j] = mfma16(af[i], bfr[j], acc[i][j]);
    }
    __syncthreads();
  }

#pragma unroll
  for (int i = 0; i < 4; ++i) {
    int rb = m0 + wm + i * 16 + ((lane >> 4) << 2);
#pragma unroll
    for (int j = 0; j < 4; ++j) {
      int cb = n0 + wn + j * 16 + (lane & 15);
#pragma unroll
      for (int r = 0; r < 4; ++r)
        Cout[(size_t)(rb + r) * 4096 + cb] = acc[i][j][r];
    }
  }
}

extern "C" void kernel_launch(void* const* d_in, const int* in_sizes, int n_in,
                              void* d_out, int out_size, void* d_ws, size_t ws_size,
                              hipStream_t stream) {
  const float* hs = (const float*)d_in[0];
  const float* Wq = (const float*)d_in[1];
  const float* Wk = (const float*)d_in[2];
  const float* Wv = (const float*)d_in[3];
  const float* Wo = (const float*)d_in[4];
  const int* pos = (const int*)d_in[7];

  unsigned short* hsb = (unsigned short*)d_ws;              // 8M
  unsigned short* Wqb = hsb + (size_t)8  * 1024 * 1024;     // 16M
  unsigned short* Wkb = Wqb + (size_t)16 * 1024 * 1024;     // 4M
  unsigned short* Wvb = Wkb + (size_t)4  * 1024 * 1024;     // 4M
  unsigned short* Wob = Wvb + (size_t)4  * 1024 * 1024;     // 16M
  unsigned short* Qb  = Wob + (size_t)16 * 1024 * 1024;     // 8M
  unsigned short* Kb  = Qb  + (size_t)8  * 1024 * 1024;     // 2M
  unsigned short* Vb  = Kb  + (size_t)2  * 1024 * 1024;     // 2M
  unsigned short* Ob  = Vb  + (size_t)2  * 1024 * 1024;     // 8M
  unsigned short* VtG = hsb;  // aliases hsb (dead after QKV GEMM; cvt rewrites)
  float* out = (float*)d_out;

  cvt5_kernel<<<dim3(2048), 256, 0, stream>>>(
      hs, Wq, Wk, Wv, Wo, hsb, Wqb, Wkb, Wvb, Wob,
      2 * 1024 * 1024, 4 * 1024 * 1024, 1 * 1024 * 1024, 1 * 1024 * 1024,
      4 * 1024 * 1024);

  gemm_qkv_8ph<<<dim3(192), 512, 0, stream>>>(hsb, Wqb, Wkb, Wvb, Qb, Kb, Vb);

  const int npairs = 2048 * 32 * 64 + 2048 * 8 * 64;
  const int rope_blocks = (npairs + 255) / 256;
  postproc_kernel<<<dim3(512 + rope_blocks), 256, 0, stream>>>(Vb, VtG, Qb, Kb, pos);

  attn_kernel<<<dim3(512), 512, 0, stream>>>(Qb, Kb, VtG, Ob);
  gemm_out_bf16<<<dim3(512), 256, 0, stream>>>(Ob, Wob, out);
}